// Round 1
// baseline (1715.274 us; speedup 1.0000x reference)
//
#include <hip/hip_runtime.h>

// ---------------------------------------------------------------------------
// GCN autoencoder:
//   h  = relu(N·(x W1) + b1)        N = D^-1/2 (A+I) D^-1/2 (sym norm, self-loop w=1)
//   z  = N·(h W2) + b2
//   h2 = relu((N·z) W3 + b3)        (aggregate-first: in_dim 128 < out_dim 512)
//   xr = N·(h2 W4) + b4
// outputs: [x_recon (50000x512), z (50000x128)] flat fp32
// ---------------------------------------------------------------------------

// ---------------- graph preprocessing ----------------

__global__ void deg_hist_kernel(const int* __restrict__ dst, const float* __restrict__ ew,
                                float* __restrict__ deg, int* __restrict__ cnt, int E) {
  int e = blockIdx.x * blockDim.x + threadIdx.x;
  if (e >= E) return;
  int d = dst[e];
  atomicAdd(&deg[d], ew[e]);
  atomicAdd(&cnt[d], 1);
}

__global__ void dinv_kernel(const float* __restrict__ deg, float* __restrict__ dinv, int n) {
  int i = blockIdx.x * blockDim.x + threadIdx.x;
  if (i >= n) return;
  dinv[i] = rsqrtf(deg[i] + 1.0f);  // deg+selfloop >= 1 > 0 always
}

__global__ void block_sums_kernel(const int* __restrict__ cnt, int* __restrict__ sums, int n) {
  __shared__ int sh[512];
  int i = blockIdx.x * 512 + threadIdx.x;
  sh[threadIdx.x] = (i < n) ? cnt[i] : 0;
  __syncthreads();
  for (int s = 256; s > 0; s >>= 1) {
    if (threadIdx.x < s) sh[threadIdx.x] += sh[threadIdx.x + s];
    __syncthreads();
  }
  if (threadIdx.x == 0) sums[blockIdx.x] = sh[0];
}

__global__ void scan_sums_kernel(int* sums, int nb) {
  if (threadIdx.x == 0 && blockIdx.x == 0) {
    int acc = 0;
    for (int i = 0; i < nb; ++i) { int v = sums[i]; sums[i] = acc; acc += v; }
  }
}

__global__ void scan_final_kernel(const int* __restrict__ cnt, const int* __restrict__ sums,
                                  int* __restrict__ rowPtr, int* __restrict__ fill, int n) {
  __shared__ int sh[512];
  int i = blockIdx.x * 512 + threadIdx.x;
  int v = (i < n) ? cnt[i] : 0;
  sh[threadIdx.x] = v;
  __syncthreads();
  for (int off = 1; off < 512; off <<= 1) {
    int y = (threadIdx.x >= off) ? sh[threadIdx.x - off] : 0;
    __syncthreads();
    sh[threadIdx.x] += y;
    __syncthreads();
  }
  if (i < n) {
    int incl = sh[threadIdx.x];
    int base = sums[blockIdx.x];
    int excl = base + incl - v;
    rowPtr[i] = excl;
    fill[i] = excl;
    if (i == n - 1) rowPtr[n] = base + incl;  // = E
  }
}

__global__ void scatter_edges_kernel(const int* __restrict__ src, const int* __restrict__ dst,
                                     const float* __restrict__ ew, const float* __restrict__ dinv,
                                     int* __restrict__ fill, int* __restrict__ col,
                                     float* __restrict__ val, int E) {
  int e = blockIdx.x * blockDim.x + threadIdx.x;
  if (e >= E) return;
  int s = src[e], d = dst[e];
  int p = atomicAdd(&fill[d], 1);
  col[p] = s;
  val[p] = dinv[s] * ew[e] * dinv[d];
}

// ---------------- aggregation: out[i] = sum_e val[e]*xw[col[e]] + dinv[i]^2*xw[i] (+b)(relu) ----

template <int DIM, int NT, bool RELU, bool BIAS>
__global__ __launch_bounds__(NT) void agg_kernel(
    const float* __restrict__ xw, const int* __restrict__ col, const float* __restrict__ val,
    const int* __restrict__ rowPtr, const float* __restrict__ dinv,
    const float* __restrict__ bias, float* __restrict__ out, int n) {
  int node = blockIdx.x;
  if (node >= n) return;
  int t = threadIdx.x;
  int beg = rowPtr[node], end = rowPtr[node + 1];
  constexpr int PT = DIM / NT;
  float acc[PT];
#pragma unroll
  for (int q = 0; q < PT; ++q) acc[q] = 0.f;
  for (int e = beg; e < end; ++e) {
    int s = col[e];
    float v = val[e];
    const float* row = xw + (size_t)s * DIM;
#pragma unroll
    for (int q = 0; q < PT; ++q) acc[q] += v * row[t + q * NT];
  }
  float di = dinv[node];
  float sl = di * di;
  const float* srow = xw + (size_t)node * DIM;
  float* orow = out + (size_t)node * DIM;
#pragma unroll
  for (int q = 0; q < PT; ++q) {
    float r = acc[q] + sl * srow[t + q * NT];
    if (BIAS) r += bias[t + q * NT];
    if (RELU) r = fmaxf(r, 0.f);
    orow[t + q * NT] = r;
  }
}

// ---------------- fp32 GEMM: C[M,N] = A[M,K]·B[K,N] (+bias)(relu) ----------
// BM=BN=128, BK=16, 256 threads, 8x8 per thread (split 4+4 rows/cols for bank-friendly LDS)

template <bool BIAS, bool RELU>
__global__ __launch_bounds__(256) void sgemm_kernel(
    const float* __restrict__ A, const float* __restrict__ B, const float* __restrict__ bias,
    float* __restrict__ C, int M, int N, int K) {
  __shared__ alignas(16) float As[16][128];  // As[k][m]
  __shared__ alignas(16) float Bs[16][128];  // Bs[k][n]
  const int bm = blockIdx.y * 128;
  const int bn = blockIdx.x * 128;
  const int tid = threadIdx.x;
  const int tx = tid & 15;
  const int ty = tid >> 4;

  float acc[8][8];
#pragma unroll
  for (int i = 0; i < 8; ++i)
#pragma unroll
    for (int j = 0; j < 8; ++j) acc[i][j] = 0.f;

  for (int bk = 0; bk < K; bk += 16) {
    // A tile 128x16 -> transposed into As[k][m]; 512 float4s, 2 per thread
#pragma unroll
    for (int l = 0; l < 2; ++l) {
      int j = tid + l * 256;
      int r = j >> 2, c4 = (j & 3) << 2;
      int gr = bm + r;
      float4 v = make_float4(0.f, 0.f, 0.f, 0.f);
      if (gr < M) v = *(const float4*)(A + (size_t)gr * K + bk + c4);
      As[c4 + 0][r] = v.x;
      As[c4 + 1][r] = v.y;
      As[c4 + 2][r] = v.z;
      As[c4 + 3][r] = v.w;
    }
    // B tile 16x128 natural layout
#pragma unroll
    for (int l = 0; l < 2; ++l) {
      int j = tid + l * 256;
      int r = j >> 5, c4 = (j & 31) << 2;
      *(float4*)&Bs[r][c4] = *(const float4*)(B + (size_t)(bk + r) * N + bn + c4);
    }
    __syncthreads();
#pragma unroll
    for (int k = 0; k < 16; ++k) {
      float a[8], b[8];
      *(float4*)&a[0] = *(const float4*)&As[k][ty * 4];
      *(float4*)&a[4] = *(const float4*)&As[k][64 + ty * 4];
      *(float4*)&b[0] = *(const float4*)&Bs[k][tx * 4];
      *(float4*)&b[4] = *(const float4*)&Bs[k][64 + tx * 4];
#pragma unroll
      for (int i = 0; i < 8; ++i)
#pragma unroll
        for (int j2 = 0; j2 < 8; ++j2) acc[i][j2] += a[i] * b[j2];
    }
    __syncthreads();
  }

#pragma unroll
  for (int i = 0; i < 8; ++i) {
    int gr = bm + ((i < 4) ? (ty * 4 + i) : (64 + ty * 4 + (i - 4)));
    if (gr >= M) continue;
#pragma unroll
    for (int half = 0; half < 2; ++half) {
      int gc = bn + half * 64 + tx * 4;
      float4 o;
      o.x = acc[i][half * 4 + 0];
      o.y = acc[i][half * 4 + 1];
      o.z = acc[i][half * 4 + 2];
      o.w = acc[i][half * 4 + 3];
      if (BIAS) {
        o.x += bias[gc + 0]; o.y += bias[gc + 1]; o.z += bias[gc + 2]; o.w += bias[gc + 3];
      }
      if (RELU) {
        o.x = fmaxf(o.x, 0.f); o.y = fmaxf(o.y, 0.f);
        o.z = fmaxf(o.z, 0.f); o.w = fmaxf(o.w, 0.f);
      }
      *(float4*)(C + (size_t)gr * N + gc) = o;
    }
  }
}

// ---------------------------------------------------------------------------

extern "C" void kernel_launch(void* const* d_in, const int* in_sizes, int n_in,
                              void* d_out, int out_size, void* d_ws, size_t ws_size,
                              hipStream_t stream) {
  const float* x  = (const float*)d_in[0];
  const int*   ei = (const int*)d_in[1];   // [2,E] flat: src then dst (jax default int32)
  const float* ew = (const float*)d_in[2];
  const float* W1 = (const float*)d_in[3];
  const float* b1 = (const float*)d_in[4];
  const float* W2 = (const float*)d_in[5];
  const float* b2 = (const float*)d_in[6];
  const float* W3 = (const float*)d_in[7];
  const float* b3 = (const float*)d_in[8];
  const float* W4 = (const float*)d_in[9];
  const float* b4 = (const float*)d_in[10];

  const int n = in_sizes[0] / 512;  // 50000
  const int E = in_sizes[2];        // 800000

  float* out   = (float*)d_out;
  float* z_out = out + (size_t)n * 512;  // z region [n,128]

  // ---- workspace layout (~136 MB) ----
  char* w = (char*)d_ws;
  auto alloc = [&](size_t bytes) {
    char* p = w;
    w += (bytes + 255) & ~(size_t)255;
    return p;
  };
  float* deg    = (float*)alloc((size_t)n * 4);
  float* dinv   = (float*)alloc((size_t)n * 4);
  int*   cnt    = (int*)alloc((size_t)n * 4);
  int*   rowPtr = (int*)alloc((size_t)(n + 1) * 4);
  int*   fill   = (int*)alloc((size_t)n * 4);
  int*   sums   = (int*)alloc(4096);
  int*   col    = (int*)alloc((size_t)E * 4);
  float* val    = (float*)alloc((size_t)E * 4);
  float* sbuf   = (float*)alloc((size_t)n * 128 * 4);  // xw2, then aggz
  float* bufA   = (float*)alloc((size_t)n * 512 * 4);  // xw1, then xw4

  const int* src = ei;
  const int* dst = ei + E;

  // ---- graph preprocessing ----
  hipMemsetAsync(deg, 0, (size_t)n * 4, stream);
  hipMemsetAsync(cnt, 0, (size_t)n * 4, stream);
  deg_hist_kernel<<<(E + 255) / 256, 256, 0, stream>>>(dst, ew, deg, cnt, E);
  dinv_kernel<<<(n + 255) / 256, 256, 0, stream>>>(deg, dinv, n);
  int NB = (n + 511) / 512;
  block_sums_kernel<<<NB, 512, 0, stream>>>(cnt, sums, n);
  scan_sums_kernel<<<1, 64, 0, stream>>>(sums, NB);
  scan_final_kernel<<<NB, 512, 0, stream>>>(cnt, sums, rowPtr, fill, n);
  scatter_edges_kernel<<<(E + 255) / 256, 256, 0, stream>>>(src, dst, ew, dinv, fill, col, val, E);

  const int MB = (n + 127) / 128;  // 391
  dim3 g512(4, MB), g128(1, MB);

  // ---- layer 1: xw1 = x@W1 -> bufA ; h = relu(N·xw1 + b1) -> d_out[0:25.6M] ----
  sgemm_kernel<false, false><<<g512, 256, 0, stream>>>(x, W1, nullptr, bufA, n, 512, 512);
  agg_kernel<512, 256, true, true><<<n, 256, 0, stream>>>(bufA, col, val, rowPtr, dinv, b1, out, n);

  // ---- layer 2: xw2 = h@W2 -> sbuf ; z = N·xw2 + b2 -> z_out ----
  sgemm_kernel<false, false><<<g128, 256, 0, stream>>>(out, W2, nullptr, sbuf, n, 128, 512);
  agg_kernel<128, 128, false, true><<<n, 128, 0, stream>>>(sbuf, col, val, rowPtr, dinv, b2, z_out, n);

  // ---- layer 3: aggz = N·z -> sbuf ; h2 = relu(aggz@W3 + b3) -> d_out[0:25.6M] (h dead) ----
  agg_kernel<128, 128, false, false><<<n, 128, 0, stream>>>(z_out, col, val, rowPtr, dinv, nullptr, sbuf, n);
  sgemm_kernel<true, true><<<g512, 256, 0, stream>>>(sbuf, W3, b3, out, n, 512, 128);

  // ---- layer 4: xw4 = h2@W4 -> bufA ; x_recon = N·xw4 + b4 -> d_out[0:25.6M] (h2 dead) ----
  sgemm_kernel<false, false><<<g512, 256, 0, stream>>>(out, W4, nullptr, bufA, n, 512, 512);
  agg_kernel<512, 256, false, true><<<n, 256, 0, stream>>>(bufA, col, val, rowPtr, dinv, b4, out, n);
}

// Round 2
// 891.681 us; speedup vs baseline: 1.9236x; 1.9236x over previous
//
#include <hip/hip_runtime.h>

// ---------------------------------------------------------------------------
// GCN autoencoder, bf16-MFMA edition.
//   GEMMs: mfma_f32_16x16x32_bf16, A = bf16 activations (row-major),
//          B = weights split hi+lo bf16 (pre-tiled k-contiguous chunks)
//          => effectively fp32-accurate on the weight side.
//   Aggregation: CSR gather-sum over bf16 rows, fp32 accumulate.
// ---------------------------------------------------------------------------

typedef short bf16x8 __attribute__((ext_vector_type(8)));
typedef float f32x4 __attribute__((ext_vector_type(4)));

__device__ __forceinline__ float bf2f(unsigned short u) {
  return __uint_as_float(((unsigned int)u) << 16);
}
__device__ __forceinline__ unsigned short f2bf(float f) {
  unsigned int u = __float_as_uint(f);
  return (unsigned short)((u + 0x7fffu + ((u >> 16) & 1u)) >> 16);  // RNE
}

// ---------------- graph preprocessing (CSR by dst) ----------------

__global__ void deg_hist_kernel(const int* __restrict__ dst, const float* __restrict__ ew,
                                float* __restrict__ deg, int* __restrict__ cnt, int E) {
  int e = blockIdx.x * blockDim.x + threadIdx.x;
  if (e >= E) return;
  int d = dst[e];
  atomicAdd(&deg[d], ew[e]);
  atomicAdd(&cnt[d], 1);
}

__global__ void dinv_kernel(const float* __restrict__ deg, float* __restrict__ dinv, int n) {
  int i = blockIdx.x * blockDim.x + threadIdx.x;
  if (i >= n) return;
  dinv[i] = rsqrtf(deg[i] + 1.0f);
}

__global__ void block_sums_kernel(const int* __restrict__ cnt, int* __restrict__ sums, int n) {
  __shared__ int sh[512];
  int i = blockIdx.x * 512 + threadIdx.x;
  sh[threadIdx.x] = (i < n) ? cnt[i] : 0;
  __syncthreads();
  for (int s = 256; s > 0; s >>= 1) {
    if (threadIdx.x < s) sh[threadIdx.x] += sh[threadIdx.x + s];
    __syncthreads();
  }
  if (threadIdx.x == 0) sums[blockIdx.x] = sh[0];
}

__global__ void scan_sums_kernel(int* sums, int nb) {
  if (threadIdx.x == 0 && blockIdx.x == 0) {
    int acc = 0;
    for (int i = 0; i < nb; ++i) { int v = sums[i]; sums[i] = acc; acc += v; }
  }
}

__global__ void scan_final_kernel(const int* __restrict__ cnt, const int* __restrict__ sums,
                                  int* __restrict__ rowPtr, int* __restrict__ fill, int n) {
  __shared__ int sh[512];
  int i = blockIdx.x * 512 + threadIdx.x;
  int v = (i < n) ? cnt[i] : 0;
  sh[threadIdx.x] = v;
  __syncthreads();
  for (int off = 1; off < 512; off <<= 1) {
    int y = (threadIdx.x >= off) ? sh[threadIdx.x - off] : 0;
    __syncthreads();
    sh[threadIdx.x] += y;
    __syncthreads();
  }
  if (i < n) {
    int incl = sh[threadIdx.x];
    int base = sums[blockIdx.x];
    int excl = base + incl - v;
    rowPtr[i] = excl;
    fill[i] = excl;
    if (i == n - 1) rowPtr[n] = base + incl;
  }
}

__global__ void scatter_edges_kernel(const int* __restrict__ src, const int* __restrict__ dst,
                                     const float* __restrict__ ew, const float* __restrict__ dinv,
                                     int* __restrict__ fill, int* __restrict__ col,
                                     float* __restrict__ val, int E) {
  int e = blockIdx.x * blockDim.x + threadIdx.x;
  if (e >= E) return;
  int s = src[e], d = dst[e];
  int p = atomicAdd(&fill[d], 1);
  col[p] = s;
  val[p] = dinv[s] * ew[e] * dinv[d];
}

// ---------------- weight transpose + hi/lo split + tile ----------------
// out layout: [N/16][K/8][16 cols][8 k] bf16 (16B chunk = 8 consecutive k of one col)

__global__ void tile_w_kernel(const float* __restrict__ W, short* __restrict__ hi,
                              short* __restrict__ lo, int K, int N) {
  int g = blockIdx.x * 256 + threadIdx.x;  // chunk id
  int total = (K >> 3) * N;
  if (g >= total) return;
  int per_nb = (K >> 3) * 16;
  int nb = g / per_nb;
  int rem = g - nb * per_nb;
  int kg = rem >> 4;
  int c = rem & 15;
  int ncol = nb * 16 + c;
  bf16x8 h8, l8;
#pragma unroll
  for (int j = 0; j < 8; ++j) {
    float w = W[(size_t)(kg * 8 + j) * N + ncol];
    unsigned short hu = f2bf(w);
    float r = w - bf2f(hu);
    h8[j] = (short)hu;
    l8[j] = (short)f2bf(r);
  }
  *(bf16x8*)(hi + (size_t)g * 8) = h8;
  *(bf16x8*)(lo + (size_t)g * 8) = l8;
}

// ---------------- MFMA GEMM: C[M,N] (bf16) = A[M,K] * (Bhi+Blo) ----------------
// grid (N/128, Mpad/128), 256 threads = 4 waves, wave tile 64x64.
// No LDS: A frags from row-major global (bf16 or fp32), B frags from tiled chunks.

template <bool AF32, bool BIAS, bool RELU>
__global__ __launch_bounds__(256) void mfma_gemm(
    const void* __restrict__ Aptr, const short* __restrict__ Bhi,
    const short* __restrict__ Blo, const float* __restrict__ bias,
    unsigned short* __restrict__ C, int M, int N, int K) {
  const int lane = threadIdx.x & 63;
  const int wave = threadIdx.x >> 6;
  const int rowbase = blockIdx.y * 128 + (wave >> 1) * 64;
  const int colbase = blockIdx.x * 128 + (wave & 1) * 64;
  const int lr = lane & 15;
  const int lk = lane >> 4;

  f32x4 acc[4][4];
#pragma unroll
  for (int i = 0; i < 4; ++i)
#pragma unroll
    for (int j = 0; j < 4; ++j) {
      f32x4 z = {0.f, 0.f, 0.f, 0.f};
      acc[i][j] = z;
    }

  size_t aoff[4];
#pragma unroll
  for (int rb = 0; rb < 4; ++rb) {
    int r = rowbase + rb * 16 + lr;
    r = (r < M) ? r : (M - 1);  // clamp: pad rows re-read last real row
    aoff[rb] = (size_t)r * K + lk * 8;
  }
  size_t boff[4];
#pragma unroll
  for (int cb = 0; cb < 4; ++cb)
    boff[cb] = ((size_t)((colbase >> 4) + cb) * (K >> 3) + lk) * 128 + lr * 8;

  for (int bk = 0; bk < K; bk += 32) {
    bf16x8 a[4], bh[4], bl[4];
#pragma unroll
    for (int rb = 0; rb < 4; ++rb) {
      if (AF32) {
        const float* ap = (const float*)Aptr + aoff[rb] + bk;
        float4 f0 = *(const float4*)ap;
        float4 f1 = *(const float4*)(ap + 4);
        bf16x8 t;
        t[0] = (short)f2bf(f0.x); t[1] = (short)f2bf(f0.y);
        t[2] = (short)f2bf(f0.z); t[3] = (short)f2bf(f0.w);
        t[4] = (short)f2bf(f1.x); t[5] = (short)f2bf(f1.y);
        t[6] = (short)f2bf(f1.z); t[7] = (short)f2bf(f1.w);
        a[rb] = t;
      } else {
        a[rb] = *(const bf16x8*)((const short*)Aptr + aoff[rb] + bk);
      }
    }
#pragma unroll
    for (int cb = 0; cb < 4; ++cb) {
      size_t o = boff[cb] + (size_t)bk * 16;
      bh[cb] = *(const bf16x8*)(Bhi + o);
      bl[cb] = *(const bf16x8*)(Blo + o);
    }
#pragma unroll
    for (int rb = 0; rb < 4; ++rb)
#pragma unroll
      for (int cb = 0; cb < 4; ++cb) {
        acc[rb][cb] = __builtin_amdgcn_mfma_f32_16x16x32_bf16(a[rb], bh[cb], acc[rb][cb], 0, 0, 0);
        acc[rb][cb] = __builtin_amdgcn_mfma_f32_16x16x32_bf16(a[rb], bl[cb], acc[rb][cb], 0, 0, 0);
      }
  }

  // epilogue: C/D layout col=lane&15, row=(lane>>4)*4+i  [verified m89/m91]
#pragma unroll
  for (int cb = 0; cb < 4; ++cb) {
    int colg = colbase + cb * 16 + lr;
    float badd = BIAS ? bias[colg] : 0.0f;
#pragma unroll
    for (int rb = 0; rb < 4; ++rb) {
#pragma unroll
      for (int i = 0; i < 4; ++i) {
        int row = rowbase + rb * 16 + lk * 4 + i;
        float v = acc[rb][cb][i] + badd;
        if (RELU) v = fmaxf(v, 0.f);
        C[(size_t)row * N + colg] = f2bf(v);
      }
    }
  }
}

// ---------------- aggregation: out[i] = sum_e val[e]*xw[col[e]] + dinv^2*xw[i] ----
// wave-per-node, 4 nodes per 256-thread block. DIM = PT*64.

template <int PT, bool INF32>
__device__ __forceinline__ void load_row(const void* p, size_t off, float* xv) {
  if (INF32) {
    if (PT == 2) {
      float2 f = *(const float2*)((const float*)p + off);
      xv[0] = f.x; xv[1] = f.y;
    } else {
      float4 f0 = *(const float4*)((const float*)p + off);
      float4 f1 = *(const float4*)((const float*)p + off + 4);
      xv[0] = f0.x; xv[1] = f0.y; xv[2] = f0.z; xv[3] = f0.w;
      xv[4] = f1.x; xv[5] = f1.y; xv[6] = f1.z; xv[7] = f1.w;
    }
  } else {
    if (PT == 2) {
      unsigned int u = *(const unsigned int*)((const unsigned short*)p + off);
      xv[0] = bf2f((unsigned short)(u & 0xffffu));
      xv[1] = bf2f((unsigned short)(u >> 16));
    } else {
      bf16x8 r = *(const bf16x8*)((const short*)p + off);
#pragma unroll
      for (int j = 0; j < 8; ++j) xv[j] = bf2f((unsigned short)r[j]);
    }
  }
}

template <int PT, bool INF32, bool BIAS, bool RELU, bool W32, bool W16>
__global__ __launch_bounds__(256) void agg_kernel(
    const void* __restrict__ xw, const int* __restrict__ col, const float* __restrict__ val,
    const int* __restrict__ rowPtr, const float* __restrict__ dinv,
    const float* __restrict__ bias, float* __restrict__ out32,
    unsigned short* __restrict__ out16, int n) {
  const int DIM = PT * 64;
  int node = blockIdx.x * 4 + (threadIdx.x >> 6);
  if (node >= n) return;
  int t = threadIdx.x & 63;
  float acc[PT];
#pragma unroll
  for (int q = 0; q < PT; ++q) acc[q] = 0.f;

  int beg = rowPtr[node], end = rowPtr[node + 1];
  for (int e = beg; e < end; ++e) {
    int s = col[e];
    float v = val[e];
    float xv[PT];
    load_row<PT, INF32>(xw, (size_t)s * DIM + t * PT, xv);
#pragma unroll
    for (int q = 0; q < PT; ++q) acc[q] += v * xv[q];
  }
  float di = dinv[node];
  float sl = di * di;
  {
    float xv[PT];
    load_row<PT, INF32>(xw, (size_t)node * DIM + t * PT, xv);
#pragma unroll
    for (int q = 0; q < PT; ++q) acc[q] += sl * xv[q];
  }
  if (BIAS) {
#pragma unroll
    for (int q = 0; q < PT; ++q) acc[q] += bias[t * PT + q];
  }
  if (RELU) {
#pragma unroll
    for (int q = 0; q < PT; ++q) acc[q] = fmaxf(acc[q], 0.f);
  }
  if (W32) {
    if (PT == 2) {
      float2 o; o.x = acc[0]; o.y = acc[1];
      *(float2*)(out32 + (size_t)node * DIM + t * PT) = o;
    } else {
      float4 o0, o1;
      o0.x = acc[0]; o0.y = acc[1]; o0.z = acc[2]; o0.w = acc[3];
      o1.x = acc[4 % PT]; o1.y = acc[5 % PT]; o1.z = acc[6 % PT]; o1.w = acc[7 % PT];
      *(float4*)(out32 + (size_t)node * DIM + t * PT) = o0;
      *(float4*)(out32 + (size_t)node * DIM + t * PT + 4) = o1;
    }
  }
  if (W16) {
    if (PT == 2) {
      unsigned int u = (unsigned int)f2bf(acc[0]) | ((unsigned int)f2bf(acc[1]) << 16);
      *(unsigned int*)(out16 + (size_t)node * DIM + t * PT) = u;
    } else {
      bf16x8 o;
#pragma unroll
      for (int j = 0; j < PT; ++j) o[j % 8] = (short)f2bf(acc[j]);
      *(bf16x8*)(out16 + (size_t)node * DIM + t * PT) = o;
    }
  }
}

// ---------------------------------------------------------------------------

extern "C" void kernel_launch(void* const* d_in, const int* in_sizes, int n_in,
                              void* d_out, int out_size, void* d_ws, size_t ws_size,
                              hipStream_t stream) {
  const float* x  = (const float*)d_in[0];
  const int*   ei = (const int*)d_in[1];
  const float* ew = (const float*)d_in[2];
  const float* W1 = (const float*)d_in[3];
  const float* b1 = (const float*)d_in[4];
  const float* W2 = (const float*)d_in[5];
  const float* b2 = (const float*)d_in[6];
  const float* W3 = (const float*)d_in[7];
  const float* b3 = (const float*)d_in[8];
  const float* W4 = (const float*)d_in[9];
  const float* b4 = (const float*)d_in[10];

  const int n = in_sizes[0] / 512;         // 50000
  const int E = in_sizes[2];               // 800000
  const int MB128 = (n + 127) / 128;       // 391
  const int Mpad = MB128 * 128;            // 50048

  float* out   = (float*)d_out;
  float* z_out = out + (size_t)n * 512;

  // ---- workspace layout (~125 MB) ----
  char* w = (char*)d_ws;
  auto alloc = [&](size_t bytes) {
    char* p = w;
    w += (bytes + 255) & ~(size_t)255;
    return p;
  };
  float* deg    = (float*)alloc((size_t)n * 4);
  float* dinv   = (float*)alloc((size_t)n * 4);
  int*   cnt    = (int*)alloc((size_t)n * 4);
  int*   rowPtr = (int*)alloc((size_t)(n + 1) * 4);
  int*   fill   = (int*)alloc((size_t)n * 4);
  int*   sums   = (int*)alloc(4096);
  int*   col    = (int*)alloc((size_t)E * 4);
  float* val    = (float*)alloc((size_t)E * 4);
  short* whi1 = (short*)alloc((size_t)512 * 512 * 2);
  short* wlo1 = (short*)alloc((size_t)512 * 512 * 2);
  short* whi2 = (short*)alloc((size_t)512 * 128 * 2);
  short* wlo2 = (short*)alloc((size_t)512 * 128 * 2);
  short* whi3 = (short*)alloc((size_t)128 * 512 * 2);
  short* wlo3 = (short*)alloc((size_t)128 * 512 * 2);
  short* whi4 = (short*)alloc((size_t)512 * 512 * 2);
  short* wlo4 = (short*)alloc((size_t)512 * 512 * 2);
  unsigned short* T1 = (unsigned short*)alloc((size_t)Mpad * 128 * 2);  // xw2 -> aggz
  unsigned short* S1 = (unsigned short*)alloc((size_t)Mpad * 512 * 2);  // xw1 -> h2
  unsigned short* S2 = (unsigned short*)alloc((size_t)Mpad * 512 * 2);  // h   -> xw4

  unsigned short* xw1  = S1;
  unsigned short* h    = S2;
  unsigned short* xw2  = T1;
  unsigned short* aggz = T1;
  unsigned short* h2   = S1;
  unsigned short* xw4  = S2;

  const int* srcp = ei;
  const int* dstp = ei + E;

  // ---- graph preprocessing ----
  hipMemsetAsync(deg, 0, (size_t)n * 4, stream);
  hipMemsetAsync(cnt, 0, (size_t)n * 4, stream);
  deg_hist_kernel<<<(E + 255) / 256, 256, 0, stream>>>(dstp, ew, deg, cnt, E);
  dinv_kernel<<<(n + 255) / 256, 256, 0, stream>>>(deg, dinv, n);
  int NB = (n + 511) / 512;
  block_sums_kernel<<<NB, 512, 0, stream>>>(cnt, sums, n);
  scan_sums_kernel<<<1, 64, 0, stream>>>(sums, NB);
  scan_final_kernel<<<NB, 512, 0, stream>>>(cnt, sums, rowPtr, fill, n);
  scatter_edges_kernel<<<(E + 255) / 256, 256, 0, stream>>>(srcp, dstp, ew, dinv, fill, col, val, E);

  // ---- weight tiling (hi/lo split) ----
  tile_w_kernel<<<(512 * 512 / 8 + 255) / 256, 256, 0, stream>>>(W1, whi1, wlo1, 512, 512);
  tile_w_kernel<<<(512 * 128 / 8 + 255) / 256, 256, 0, stream>>>(W2, whi2, wlo2, 512, 128);
  tile_w_kernel<<<(128 * 512 / 8 + 255) / 256, 256, 0, stream>>>(W3, whi3, wlo3, 128, 512);
  tile_w_kernel<<<(512 * 512 / 8 + 255) / 256, 256, 0, stream>>>(W4, whi4, wlo4, 512, 512);

  const int AGB = (n + 3) / 4;  // 12500

  // ---- layer 1: xw1 = x@W1 ; h = relu(N.xw1 + b1) ----
  mfma_gemm<true, false, false><<<dim3(4, MB128), 256, 0, stream>>>(
      x, whi1, wlo1, nullptr, xw1, n, 512, 512);
  agg_kernel<8, false, true, true, false, true><<<AGB, 256, 0, stream>>>(
      xw1, col, val, rowPtr, dinv, b1, nullptr, h, n);

  // ---- layer 2: xw2 = h@W2 ; z = N.xw2 + b2 (fp32 to d_out) ----
  mfma_gemm<false, false, false><<<dim3(1, MB128), 256, 0, stream>>>(
      h, whi2, wlo2, nullptr, xw2, n, 128, 512);
  agg_kernel<2, false, true, false, true, false><<<AGB, 256, 0, stream>>>(
      xw2, col, val, rowPtr, dinv, b2, z_out, nullptr, n);

  // ---- layer 3: aggz = N.z ; h2 = relu(aggz@W3 + b3) ----
  agg_kernel<2, true, false, false, false, true><<<AGB, 256, 0, stream>>>(
      z_out, col, val, rowPtr, dinv, nullptr, nullptr, aggz, n);
  mfma_gemm<false, true, true><<<dim3(4, MB128), 256, 0, stream>>>(
      aggz, whi3, wlo3, b3, h2, n, 512, 128);

  // ---- layer 4: xw4 = h2@W4 ; x_recon = N.xw4 + b4 (fp32 to d_out) ----
  mfma_gemm<false, false, false><<<dim3(4, MB128), 256, 0, stream>>>(
      h2, whi4, wlo4, nullptr, xw4, n, 512, 512);
  agg_kernel<8, false, true, false, true, false><<<AGB, 256, 0, stream>>>(
      xw4, col, val, rowPtr, dinv, b4, out, nullptr, n);
}

// Round 3
// 710.949 us; speedup vs baseline: 2.4127x; 1.2542x over previous
//
#include <hip/hip_runtime.h>

// ---------------------------------------------------------------------------
// GCN autoencoder, LDS-staged bf16-MFMA edition (m97-style GEMM structure).
//   GEMMs: mfma_f32_16x16x32_bf16, 128x128 tile, BK=64, global_load_lds
//          staging with source-side XOR swizzle (rule #21: linear LDS dest,
//          inverse-swizzled global source, swizzled ds_read).
//   B = weights split hi+lo bf16 (fp32-accurate weight side), pre-tiled.
//   Aggregation: CSR gather-sum over bf16 rows, 4-edge unrolled.
// ---------------------------------------------------------------------------

typedef short bf16x8 __attribute__((ext_vector_type(8)));
typedef float f32x4 __attribute__((ext_vector_type(4)));

__device__ __forceinline__ float bf2f(unsigned short u) {
  return __uint_as_float(((unsigned int)u) << 16);
}
__device__ __forceinline__ unsigned short f2bf(float f) {
  unsigned int u = __float_as_uint(f);
  return (unsigned short)((u + 0x7fffu + ((u >> 16) & 1u)) >> 16);  // RNE
}

__device__ __forceinline__ void gload_lds16(const void* g, void* l) {
  __builtin_amdgcn_global_load_lds(
      (const __attribute__((address_space(1))) unsigned int*)g,
      (__attribute__((address_space(3))) unsigned int*)l, 16, 0, 0);
}

// ---------------- graph preprocessing (CSR by dst) ----------------

__global__ void deg_hist_kernel(const int* __restrict__ dst, const float* __restrict__ ew,
                                float* __restrict__ deg, int* __restrict__ cnt, int E) {
  int e = blockIdx.x * blockDim.x + threadIdx.x;
  if (e >= E) return;
  int d = dst[e];
  atomicAdd(&deg[d], ew[e]);
  atomicAdd(&cnt[d], 1);
}

__global__ void dinv_kernel(const float* __restrict__ deg, float* __restrict__ dinv, int n) {
  int i = blockIdx.x * blockDim.x + threadIdx.x;
  if (i >= n) return;
  dinv[i] = rsqrtf(deg[i] + 1.0f);
}

__global__ void block_sums_kernel(const int* __restrict__ cnt, int* __restrict__ sums, int n) {
  __shared__ int sh[512];
  int i = blockIdx.x * 512 + threadIdx.x;
  sh[threadIdx.x] = (i < n) ? cnt[i] : 0;
  __syncthreads();
  for (int s = 256; s > 0; s >>= 1) {
    if (threadIdx.x < s) sh[threadIdx.x] += sh[threadIdx.x + s];
    __syncthreads();
  }
  if (threadIdx.x == 0) sums[blockIdx.x] = sh[0];
}

__global__ void scan_sums_kernel(int* sums, int nb) {
  if (threadIdx.x == 0 && blockIdx.x == 0) {
    int acc = 0;
    for (int i = 0; i < nb; ++i) { int v = sums[i]; sums[i] = acc; acc += v; }
  }
}

__global__ void scan_final_kernel(const int* __restrict__ cnt, const int* __restrict__ sums,
                                  int* __restrict__ rowPtr, int* __restrict__ fill, int n) {
  __shared__ int sh[512];
  int i = blockIdx.x * 512 + threadIdx.x;
  int v = (i < n) ? cnt[i] : 0;
  sh[threadIdx.x] = v;
  __syncthreads();
  for (int off = 1; off < 512; off <<= 1) {
    int y = (threadIdx.x >= off) ? sh[threadIdx.x - off] : 0;
    __syncthreads();
    sh[threadIdx.x] += y;
    __syncthreads();
  }
  if (i < n) {
    int incl = sh[threadIdx.x];
    int base = sums[blockIdx.x];
    int excl = base + incl - v;
    rowPtr[i] = excl;
    fill[i] = excl;
    if (i == n - 1) rowPtr[n] = base + incl;
  }
}

__global__ void scatter_edges_kernel(const int* __restrict__ src, const int* __restrict__ dst,
                                     const float* __restrict__ ew, const float* __restrict__ dinv,
                                     int* __restrict__ fill, int* __restrict__ col,
                                     float* __restrict__ val, int E) {
  int e = blockIdx.x * blockDim.x + threadIdx.x;
  if (e >= E) return;
  int s = src[e], d = dst[e];
  int p = atomicAdd(&fill[d], 1);
  col[p] = s;
  val[p] = dinv[s] * ew[e] * dinv[d];
}

// ---------------- x -> bf16 (pad rows zeroed) ----------------

__global__ void cvt_x_kernel(const float* __restrict__ x, unsigned short* __restrict__ xbf,
                             int n, int Mpad) {
  int g = blockIdx.x * 256 + threadIdx.x;  // one 8-elem chunk per thread
  int total = Mpad * 64;                   // 512/8 chunks per row
  if (g >= total) return;
  int row = g >> 6;
  int cc = (g & 63) << 3;
  bf16x8 o;
  if (row < n) {
    const float* p = x + (size_t)row * 512 + cc;
    float4 f0 = *(const float4*)p;
    float4 f1 = *(const float4*)(p + 4);
    o[0] = (short)f2bf(f0.x); o[1] = (short)f2bf(f0.y);
    o[2] = (short)f2bf(f0.z); o[3] = (short)f2bf(f0.w);
    o[4] = (short)f2bf(f1.x); o[5] = (short)f2bf(f1.y);
    o[6] = (short)f2bf(f1.z); o[7] = (short)f2bf(f1.w);
  } else {
#pragma unroll
    for (int j = 0; j < 8; ++j) o[j] = 0;
  }
  *(bf16x8*)(xbf + (size_t)g * 8) = o;
}

// ---------------- weight hi/lo split, swizzled-tile layout ----------------
// Per (nb, kb): 1024 16B chunks. Chunk c: col = c>>3 (0..127), stored k-chunk
// kcs = c&7 holds global k-chunk (kcs ^ (col&7)) — the LDS image directly.

__global__ void tile_w_kernel(const float* __restrict__ W, short* __restrict__ hi,
                              short* __restrict__ lo, int K, int N) {
  int g = blockIdx.x * 256 + threadIdx.x;
  int kb_cnt = K >> 6;
  int total = (N >> 7) * kb_cnt * 1024;
  if (g >= total) return;
  int c = g & 1023;
  int t = g >> 10;
  int kb = t % kb_cnt;
  int nb = t / kb_cnt;
  int colg = (nb << 7) + (c >> 3);
  int k0 = (kb << 6) + (((c & 7) ^ ((c >> 3) & 7)) << 3);
  bf16x8 h8, l8;
#pragma unroll
  for (int j = 0; j < 8; ++j) {
    float w = W[(size_t)(k0 + j) * N + colg];
    unsigned short hu = f2bf(w);
    h8[j] = (short)hu;
    l8[j] = (short)f2bf(w - bf2f(hu));
  }
  *(bf16x8*)(hi + (size_t)g * 8) = h8;
  *(bf16x8*)(lo + (size_t)g * 8) = l8;
}

// ---------------- MFMA GEMM (LDS-staged): C[Mpad,N] bf16 = A * (Bhi+Blo) ----
// grid (N/128, Mpad/128), 256 thr = 4 waves (2x2), wave tile 64x64, BK=64.

template <bool BIAS, bool RELU>
__global__ __launch_bounds__(256) void mfma_gemm(
    const unsigned short* __restrict__ A, const short* __restrict__ Bhi,
    const short* __restrict__ Blo, const float* __restrict__ bias,
    unsigned short* __restrict__ C, int N, int K) {
  __shared__ short As[8192];  // [128 rows][8 kc][8] bf16, swizzled image
  __shared__ short Bh[8192];  // [128 cols][8 kc][8]
  __shared__ short Bl[8192];
  const int tid = threadIdx.x;
  const int lane = tid & 63;
  const int wave = tid >> 6;
  const int rowblk = blockIdx.y << 7;
  const int colblk = blockIdx.x << 7;
  const int wr = ((wave >> 1) << 6);
  const int wc = ((wave & 1) << 6);
  const int lr = lane & 15;
  const int lk = lane >> 4;
  const int kbN = K >> 6;

  f32x4 acc[4][4];
#pragma unroll
  for (int i = 0; i < 4; ++i)
#pragma unroll
    for (int j = 0; j < 4; ++j) {
      f32x4 z = {0.f, 0.f, 0.f, 0.f};
      acc[i][j] = z;
    }

  // A staging: issue i covers rows wave*32 + i*8 + (lane>>3); stored kcs=lane&7
  // fetches global k-chunk (lane&7)^(lane>>3)  [row&7 == lane>>3]
  const int arow = wave * 32 + (lane >> 3);
  const size_t abase = (size_t)(rowblk + arow) * K + (size_t)(((lane & 7) ^ (lane >> 3)) << 3);
  // B tiles pre-swizzled: contiguous chunks
  const size_t btile0 = ((size_t)(colblk >> 7) * kbN) << 13;  // *8192 elems
  const int bchunk = wave * 256 + lane;

  short* AsW = As + wave * 2048;
  short* BhW = Bh + wave * 2048;
  short* BlW = Bl + wave * 2048;

  for (int kb = 0; kb < kbN; ++kb) {
    const unsigned short* asrc = A + abase + (kb << 6);
    const short* bhsrc = Bhi + btile0 + ((size_t)kb << 13) + (size_t)bchunk * 8;
    const short* blsrc = Blo + btile0 + ((size_t)kb << 13) + (size_t)bchunk * 8;
#pragma unroll
    for (int i = 0; i < 4; ++i) {
      gload_lds16(asrc + (size_t)(i * 8) * K, AsW + i * 512);
      gload_lds16(bhsrc + i * 512, BhW + i * 512);
      gload_lds16(blsrc + i * 512, BlW + i * 512);
    }
    __syncthreads();
#pragma unroll
    for (int kk = 0; kk < 2; ++kk) {
      bf16x8 af[4], bhf[4], blf[4];
      const int kc = kk * 4 + lk;
#pragma unroll
      for (int rb = 0; rb < 4; ++rb) {
        int rowl = wr + rb * 16 + lr;
        af[rb] = *(const bf16x8*)(As + rowl * 64 + ((kc ^ (rowl & 7)) << 3));
      }
#pragma unroll
      for (int cb = 0; cb < 4; ++cb) {
        int coll = wc + cb * 16 + lr;
        int off = coll * 64 + ((kc ^ (coll & 7)) << 3);
        bhf[cb] = *(const bf16x8*)(Bh + off);
        blf[cb] = *(const bf16x8*)(Bl + off);
      }
#pragma unroll
      for (int rb = 0; rb < 4; ++rb)
#pragma unroll
        for (int cb = 0; cb < 4; ++cb) {
          acc[rb][cb] = __builtin_amdgcn_mfma_f32_16x16x32_bf16(af[rb], bhf[cb], acc[rb][cb], 0, 0, 0);
          acc[rb][cb] = __builtin_amdgcn_mfma_f32_16x16x32_bf16(af[rb], blf[cb], acc[rb][cb], 0, 0, 0);
        }
    }
    __syncthreads();
  }

  // epilogue: C/D layout col=lane&15, row=(lane>>4)*4+i
#pragma unroll
  for (int cb = 0; cb < 4; ++cb) {
    int colg = colblk + wc + cb * 16 + lr;
    float badd = BIAS ? bias[colg] : 0.0f;
#pragma unroll
    for (int rb = 0; rb < 4; ++rb) {
#pragma unroll
      for (int i = 0; i < 4; ++i) {
        int row = rowblk + wr + rb * 16 + lk * 4 + i;
        float v = acc[rb][cb][i] + badd;
        if (RELU) v = fmaxf(v, 0.f);
        C[(size_t)row * N + colg] = f2bf(v);
      }
    }
  }
}

// ---------------- aggregation: out[i] = sum_e val[e]*xw[col[e]] + dinv^2*xw[i] ----

template <int PT, bool INF32>
__device__ __forceinline__ void load_row(const void* p, size_t off, float* xv) {
  if (INF32) {
    if (PT == 2) {
      float2 f = *(const float2*)((const float*)p + off);
      xv[0] = f.x; xv[1] = f.y;
    } else {
      float4 f0 = *(const float4*)((const float*)p + off);
      float4 f1 = *(const float4*)((const float*)p + off + 4);
      xv[0] = f0.x; xv[1] = f0.y; xv[2] = f0.z; xv[3] = f0.w;
      xv[4] = f1.x; xv[5] = f1.y; xv[6] = f1.z; xv[7] = f1.w;
    }
  } else {
    if (PT == 2) {
      unsigned int u = *(const unsigned int*)((const unsigned short*)p + off);
      xv[0] = bf2f((unsigned short)(u & 0xffffu));
      xv[1] = bf2f((unsigned short)(u >> 16));
    } else {
      bf16x8 r = *(const bf16x8*)((const short*)p + off);
#pragma unroll
      for (int j = 0; j < 8; ++j) xv[j] = bf2f((unsigned short)r[j]);
    }
  }
}

template <int PT, bool INF32, bool BIAS, bool RELU, bool W32, bool W16>
__global__ __launch_bounds__(256) void agg_kernel(
    const void* __restrict__ xw, const int* __restrict__ col, const float* __restrict__ val,
    const int* __restrict__ rowPtr, const float* __restrict__ dinv,
    const float* __restrict__ bias, float* __restrict__ out32,
    unsigned short* __restrict__ out16, int n) {
  const int DIM = PT * 64;
  int node = blockIdx.x * 4 + (threadIdx.x >> 6);
  if (node >= n) return;
  int t = threadIdx.x & 63;
  float acc[PT];
#pragma unroll
  for (int q = 0; q < PT; ++q) acc[q] = 0.f;

  int beg = rowPtr[node], end = rowPtr[node + 1];
  int e = beg;
  for (; e + 4 <= end; e += 4) {
    int s0 = col[e + 0], s1 = col[e + 1], s2 = col[e + 2], s3 = col[e + 3];
    float v0 = val[e + 0], v1 = val[e + 1], v2 = val[e + 2], v3 = val[e + 3];
    float x0[PT], x1[PT], x2[PT], x3[PT];
    load_row<PT, INF32>(xw, (size_t)s0 * DIM + t * PT, x0);
    load_row<PT, INF32>(xw, (size_t)s1 * DIM + t * PT, x1);
    load_row<PT, INF32>(xw, (size_t)s2 * DIM + t * PT, x2);
    load_row<PT, INF32>(xw, (size_t)s3 * DIM + t * PT, x3);
#pragma unroll
    for (int q = 0; q < PT; ++q)
      acc[q] += v0 * x0[q] + v1 * x1[q] + v2 * x2[q] + v3 * x3[q];
  }
  for (; e < end; ++e) {
    int s = col[e];
    float v = val[e];
    float xv[PT];
    load_row<PT, INF32>(xw, (size_t)s * DIM + t * PT, xv);
#pragma unroll
    for (int q = 0; q < PT; ++q) acc[q] += v * xv[q];
  }
  float di = dinv[node];
  float sl = di * di;
  {
    float xv[PT];
    load_row<PT, INF32>(xw, (size_t)node * DIM + t * PT, xv);
#pragma unroll
    for (int q = 0; q < PT; ++q) acc[q] += sl * xv[q];
  }
  if (BIAS) {
#pragma unroll
    for (int q = 0; q < PT; ++q) acc[q] += bias[t * PT + q];
  }
  if (RELU) {
#pragma unroll
    for (int q = 0; q < PT; ++q) acc[q] = fmaxf(acc[q], 0.f);
  }
  if (W32) {
    if (PT == 2) {
      float2 o; o.x = acc[0]; o.y = acc[1];
      *(float2*)(out32 + (size_t)node * DIM + t * PT) = o;
    } else {
      float4 o0, o1;
      o0.x = acc[0]; o0.y = acc[1]; o0.z = acc[2]; o0.w = acc[3];
      o1.x = acc[4 % PT]; o1.y = acc[5 % PT]; o1.z = acc[6 % PT]; o1.w = acc[7 % PT];
      *(float4*)(out32 + (size_t)node * DIM + t * PT) = o0;
      *(float4*)(out32 + (size_t)node * DIM + t * PT + 4) = o1;
    }
  }
  if (W16) {
    if (PT == 2) {
      unsigned int u = (unsigned int)f2bf(acc[0]) | ((unsigned int)f2bf(acc[1]) << 16);
      *(unsigned int*)(out16 + (size_t)node * DIM + t * PT) = u;
    } else {
      bf16x8 o;
#pragma unroll
      for (int j = 0; j < PT; ++j) o[j % 8] = (short)f2bf(acc[j]);
      *(bf16x8*)(out16 + (size_t)node * DIM + t * PT) = o;
    }
  }
}

// ---------------------------------------------------------------------------

extern "C" void kernel_launch(void* const* d_in, const int* in_sizes, int n_in,
                              void* d_out, int out_size, void* d_ws, size_t ws_size,
                              hipStream_t stream) {
  const float* x  = (const float*)d_in[0];
  const int*   ei = (const int*)d_in[1];
  const float* ew = (const float*)d_in[2];
  const float* W1 = (const float*)d_in[3];
  const float* b1 = (const float*)d_in[4];
  const float* W2 = (const float*)d_in[5];
  const float* b2 = (const float*)d_in[6];
  const float* W3 = (const float*)d_in[7];
  const float* b3 = (const float*)d_in[8];
  const float* W4 = (const float*)d_in[9];
  const float* b4 = (const float*)d_in[10];

  const int n = in_sizes[0] / 512;         // 50000
  const int E = in_sizes[2];               // 800000
  const int MB128 = (n + 127) / 128;       // 391
  const int Mpad = MB128 * 128;            // 50048

  float* out   = (float*)d_out;
  float* z_out = out + (size_t)n * 512;

  // ---- workspace layout (~125 MB) ----
  char* w = (char*)d_ws;
  auto alloc = [&](size_t bytes) {
    char* p = w;
    w += (bytes + 255) & ~(size_t)255;
    return p;
  };
  float* deg    = (float*)alloc((size_t)n * 4);
  float* dinv   = (float*)alloc((size_t)n * 4);
  int*   cnt    = (int*)alloc((size_t)n * 4);
  int*   rowPtr = (int*)alloc((size_t)(n + 1) * 4);
  int*   fill   = (int*)alloc((size_t)n * 4);
  int*   sums   = (int*)alloc(4096);
  int*   col    = (int*)alloc((size_t)E * 4);
  float* val    = (float*)alloc((size_t)E * 4);
  short* whi1 = (short*)alloc((size_t)512 * 512 * 2);
  short* wlo1 = (short*)alloc((size_t)512 * 512 * 2);
  short* whi2 = (short*)alloc((size_t)512 * 128 * 2);
  short* wlo2 = (short*)alloc((size_t)512 * 128 * 2);
  short* whi3 = (short*)alloc((size_t)128 * 512 * 2);
  short* wlo3 = (short*)alloc((size_t)128 * 512 * 2);
  short* whi4 = (short*)alloc((size_t)512 * 512 * 2);
  short* wlo4 = (short*)alloc((size_t)512 * 512 * 2);
  unsigned short* T  = (unsigned short*)alloc((size_t)Mpad * 128 * 2);  // xw2 / aggz
  unsigned short* B1 = (unsigned short*)alloc((size_t)Mpad * 512 * 2);  // xbf / h / xw4
  unsigned short* B2 = (unsigned short*)alloc((size_t)Mpad * 512 * 2);  // xw1 / h2

  const int* srcp = ei;
  const int* dstp = ei + E;

  // ---- graph preprocessing ----
  hipMemsetAsync(deg, 0, (size_t)n * 4, stream);
  hipMemsetAsync(cnt, 0, (size_t)n * 4, stream);
  deg_hist_kernel<<<(E + 255) / 256, 256, 0, stream>>>(dstp, ew, deg, cnt, E);
  dinv_kernel<<<(n + 255) / 256, 256, 0, stream>>>(deg, dinv, n);
  int NB = (n + 511) / 512;
  block_sums_kernel<<<NB, 512, 0, stream>>>(cnt, sums, n);
  scan_sums_kernel<<<1, 64, 0, stream>>>(sums, NB);
  scan_final_kernel<<<NB, 512, 0, stream>>>(cnt, sums, rowPtr, fill, n);
  scatter_edges_kernel<<<(E + 255) / 256, 256, 0, stream>>>(srcp, dstp, ew, dinv, fill, col, val, E);

  // ---- weight tiling + x conversion ----
  tile_w_kernel<<<(4 * 8 * 1024 + 255) / 256, 256, 0, stream>>>(W1, whi1, wlo1, 512, 512);
  tile_w_kernel<<<(1 * 8 * 1024 + 255) / 256, 256, 0, stream>>>(W2, whi2, wlo2, 512, 128);
  tile_w_kernel<<<(4 * 2 * 1024 + 255) / 256, 256, 0, stream>>>(W3, whi3, wlo3, 128, 512);
  tile_w_kernel<<<(4 * 8 * 1024 + 255) / 256, 256, 0, stream>>>(W4, whi4, wlo4, 512, 512);
  cvt_x_kernel<<<(Mpad * 64 + 255) / 256, 256, 0, stream>>>(x, B1, n, Mpad);

  const int AGB = (n + 3) / 4;  // 12500

  // ---- layer 1: xw1 = xbf@W1 -> B2 ; h = relu(N.xw1 + b1) -> B1 ----
  mfma_gemm<false, false><<<dim3(4, MB128), 256, 0, stream>>>(B1, whi1, wlo1, nullptr, B2, 512, 512);
  agg_kernel<8, false, true, true, false, true><<<AGB, 256, 0, stream>>>(
      B2, col, val, rowPtr, dinv, b1, nullptr, B1, n);

  // ---- layer 2: xw2 = h@W2 -> T ; z = N.xw2 + b2 -> z_out (fp32) ----
  mfma_gemm<false, false><<<dim3(1, MB128), 256, 0, stream>>>(B1, whi2, wlo2, nullptr, T, 128, 512);
  agg_kernel<2, false, true, false, true, false><<<AGB, 256, 0, stream>>>(
      T, col, val, rowPtr, dinv, b2, z_out, nullptr, n);

  // ---- layer 3: aggz = N.z -> T ; h2 = relu(aggz@W3 + b3) -> B2 ----
  agg_kernel<2, true, false, false, false, true><<<AGB, 256, 0, stream>>>(
      z_out, col, val, rowPtr, dinv, nullptr, nullptr, T, n);
  mfma_gemm<true, true><<<dim3(4, MB128), 256, 0, stream>>>(T, whi3, wlo3, b3, B2, 512, 128);

  // ---- layer 4: xw4 = h2@W4 -> B1 ; x_recon = N.xw4 + b4 -> out (fp32) ----
  mfma_gemm<false, false><<<dim3(4, MB128), 256, 0, stream>>>(B2, whi4, wlo4, nullptr, B1, 512, 512);
  agg_kernel<8, false, true, false, true, false><<<AGB, 256, 0, stream>>>(
      B1, col, val, rowPtr, dinv, b4, out, nullptr, n);
}

// Round 4
// 667.856 us; speedup vs baseline: 2.5683x; 1.0645x over previous
//
#include <hip/hip_runtime.h>

// ---------------------------------------------------------------------------
// GCN autoencoder, LDS-staged bf16-MFMA edition (m97-style GEMM structure).
//   GEMMs: mfma_f32_16x16x32_bf16, 128x128 tile, BK=64, global_load_lds
//          staging with source-side XOR swizzle (rule #21: linear LDS dest,
//          inverse-swizzled global source, swizzled ds_read).
//   Weights pure bf16 (A-side bf16 rounding dominates error anyway).
//   Aggregation: CSR gather-sum over bf16 rows, 4-edge unrolled.
// ---------------------------------------------------------------------------

typedef short bf16x8 __attribute__((ext_vector_type(8)));
typedef float f32x4 __attribute__((ext_vector_type(4)));

__device__ __forceinline__ float bf2f(unsigned short u) {
  return __uint_as_float(((unsigned int)u) << 16);
}
__device__ __forceinline__ unsigned short f2bf(float f) {
  unsigned int u = __float_as_uint(f);
  return (unsigned short)((u + 0x7fffu + ((u >> 16) & 1u)) >> 16);  // RNE
}

__device__ __forceinline__ void gload_lds16(const void* g, void* l) {
  __builtin_amdgcn_global_load_lds(
      (const __attribute__((address_space(1))) unsigned int*)g,
      (__attribute__((address_space(3))) unsigned int*)l, 16, 0, 0);
}

// ---------------- graph preprocessing (CSR by dst) ----------------

__global__ void deg_hist_kernel(const int* __restrict__ dst, const float* __restrict__ ew,
                                float* __restrict__ deg, int* __restrict__ cnt, int E) {
  int e = blockIdx.x * blockDim.x + threadIdx.x;
  if (e >= E) return;
  int d = dst[e];
  atomicAdd(&deg[d], ew[e]);
  atomicAdd(&cnt[d], 1);
}

__global__ void dinv_kernel(const float* __restrict__ deg, float* __restrict__ dinv, int n) {
  int i = blockIdx.x * blockDim.x + threadIdx.x;
  if (i >= n) return;
  dinv[i] = rsqrtf(deg[i] + 1.0f);
}

__global__ void block_sums_kernel(const int* __restrict__ cnt, int* __restrict__ sums, int n) {
  __shared__ int sh[512];
  int i = blockIdx.x * 512 + threadIdx.x;
  sh[threadIdx.x] = (i < n) ? cnt[i] : 0;
  __syncthreads();
  for (int s = 256; s > 0; s >>= 1) {
    if (threadIdx.x < s) sh[threadIdx.x] += sh[threadIdx.x + s];
    __syncthreads();
  }
  if (threadIdx.x == 0) sums[blockIdx.x] = sh[0];
}

__global__ void scan_sums_kernel(int* sums, int nb) {
  if (threadIdx.x == 0 && blockIdx.x == 0) {
    int acc = 0;
    for (int i = 0; i < nb; ++i) { int v = sums[i]; sums[i] = acc; acc += v; }
  }
}

__global__ void scan_final_kernel(const int* __restrict__ cnt, const int* __restrict__ sums,
                                  int* __restrict__ rowPtr, int* __restrict__ fill, int n) {
  __shared__ int sh[512];
  int i = blockIdx.x * 512 + threadIdx.x;
  int v = (i < n) ? cnt[i] : 0;
  sh[threadIdx.x] = v;
  __syncthreads();
  for (int off = 1; off < 512; off <<= 1) {
    int y = (threadIdx.x >= off) ? sh[threadIdx.x - off] : 0;
    __syncthreads();
    sh[threadIdx.x] += y;
    __syncthreads();
  }
  if (i < n) {
    int incl = sh[threadIdx.x];
    int base = sums[blockIdx.x];
    int excl = base + incl - v;
    rowPtr[i] = excl;
    fill[i] = excl;
    if (i == n - 1) rowPtr[n] = base + incl;
  }
}

__global__ void scatter_edges_kernel(const int* __restrict__ src, const int* __restrict__ dst,
                                     const float* __restrict__ ew, const float* __restrict__ dinv,
                                     int* __restrict__ fill, int* __restrict__ col,
                                     float* __restrict__ val, int E) {
  int e = blockIdx.x * blockDim.x + threadIdx.x;
  if (e >= E) return;
  int s = src[e], d = dst[e];
  int p = atomicAdd(&fill[d], 1);
  col[p] = s;
  val[p] = dinv[s] * ew[e] * dinv[d];
}

// ---------------- x -> bf16 (pad rows zeroed) ----------------

__global__ void cvt_x_kernel(const float* __restrict__ x, unsigned short* __restrict__ xbf,
                             int n, int Mpad) {
  int g = blockIdx.x * 256 + threadIdx.x;  // one 8-elem chunk per thread
  int total = Mpad * 64;                   // 512/8 chunks per row
  if (g >= total) return;
  int row = g >> 6;
  int cc = (g & 63) << 3;
  bf16x8 o;
  if (row < n) {
    const float* p = x + (size_t)row * 512 + cc;
    float4 f0 = *(const float4*)p;
    float4 f1 = *(const float4*)(p + 4);
    o[0] = (short)f2bf(f0.x); o[1] = (short)f2bf(f0.y);
    o[2] = (short)f2bf(f0.z); o[3] = (short)f2bf(f0.w);
    o[4] = (short)f2bf(f1.x); o[5] = (short)f2bf(f1.y);
    o[6] = (short)f2bf(f1.z); o[7] = (short)f2bf(f1.w);
  } else {
#pragma unroll
    for (int j = 0; j < 8; ++j) o[j] = 0;
  }
  *(bf16x8*)(xbf + (size_t)g * 8) = o;
}

// ---------------- weight bf16 convert, swizzled-tile layout ----------------
// Per (nb, kb): 1024 16B chunks. Chunk c: col = c>>3 (0..127), stored k-chunk
// kcs = c&7 holds global k-chunk (kcs ^ (col&7)) — the LDS image directly.

__global__ void tile_w_kernel(const float* __restrict__ W, short* __restrict__ hi,
                              int K, int N) {
  int g = blockIdx.x * 256 + threadIdx.x;
  int kb_cnt = K >> 6;
  int total = (N >> 7) * kb_cnt * 1024;
  if (g >= total) return;
  int c = g & 1023;
  int t = g >> 10;
  int kb = t % kb_cnt;
  int nb = t / kb_cnt;
  int colg = (nb << 7) + (c >> 3);
  int k0 = (kb << 6) + (((c & 7) ^ ((c >> 3) & 7)) << 3);
  bf16x8 h8;
#pragma unroll
  for (int j = 0; j < 8; ++j) {
    float w = W[(size_t)(k0 + j) * N + colg];
    h8[j] = (short)f2bf(w);
  }
  *(bf16x8*)(hi + (size_t)g * 8) = h8;
}

// ---------------- MFMA GEMM (LDS-staged): C[Mpad,N] bf16 = A * B ----
// grid (N/128, Mpad/128), 256 thr = 4 waves (2x2), wave tile 64x64, BK=64.

template <bool BIAS, bool RELU>
__global__ __launch_bounds__(256) void mfma_gemm(
    const unsigned short* __restrict__ A, const short* __restrict__ Bhi,
    const float* __restrict__ bias, unsigned short* __restrict__ C, int N, int K) {
  __shared__ short As[8192];  // [128 rows][8 kc][8] bf16, swizzled image
  __shared__ short Bh[8192];  // [128 cols][8 kc][8]
  const int tid = threadIdx.x;
  const int lane = tid & 63;
  const int wave = tid >> 6;
  const int rowblk = blockIdx.y << 7;
  const int colblk = blockIdx.x << 7;
  const int wr = ((wave >> 1) << 6);
  const int wc = ((wave & 1) << 6);
  const int lr = lane & 15;
  const int lk = lane >> 4;
  const int kbN = K >> 6;

  f32x4 acc[4][4];
#pragma unroll
  for (int i = 0; i < 4; ++i)
#pragma unroll
    for (int j = 0; j < 4; ++j) {
      f32x4 z = {0.f, 0.f, 0.f, 0.f};
      acc[i][j] = z;
    }

  // A staging: issue i covers rows wave*32 + i*8 + (lane>>3); stored kcs=lane&7
  // fetches global k-chunk (lane&7)^(lane>>3)  [row&7 == lane>>3]
  const int arow = wave * 32 + (lane >> 3);
  const size_t abase = (size_t)(rowblk + arow) * K + (size_t)(((lane & 7) ^ (lane >> 3)) << 3);
  // B tiles pre-swizzled: contiguous chunks
  const size_t btile0 = ((size_t)(colblk >> 7) * kbN) << 13;  // *8192 elems
  const int bchunk = wave * 256 + lane;

  short* AsW = As + wave * 2048;
  short* BhW = Bh + wave * 2048;

  for (int kb = 0; kb < kbN; ++kb) {
    const unsigned short* asrc = A + abase + (kb << 6);
    const short* bhsrc = Bhi + btile0 + ((size_t)kb << 13) + (size_t)bchunk * 8;
#pragma unroll
    for (int i = 0; i < 4; ++i) {
      gload_lds16(asrc + (size_t)(i * 8) * K, AsW + i * 512);
      gload_lds16(bhsrc + i * 512, BhW + i * 512);
    }
    __syncthreads();
#pragma unroll
    for (int kk = 0; kk < 2; ++kk) {
      bf16x8 af[4], bhf[4];
      const int kc = kk * 4 + lk;
#pragma unroll
      for (int rb = 0; rb < 4; ++rb) {
        int rowl = wr + rb * 16 + lr;
        af[rb] = *(const bf16x8*)(As + rowl * 64 + ((kc ^ (rowl & 7)) << 3));
      }
#pragma unroll
      for (int cb = 0; cb < 4; ++cb) {
        int coll = wc + cb * 16 + lr;
        bhf[cb] = *(const bf16x8*)(Bh + coll * 64 + ((kc ^ (coll & 7)) << 3));
      }
#pragma unroll
      for (int rb = 0; rb < 4; ++rb)
#pragma unroll
        for (int cb = 0; cb < 4; ++cb)
          acc[rb][cb] = __builtin_amdgcn_mfma_f32_16x16x32_bf16(af[rb], bhf[cb], acc[rb][cb], 0, 0, 0);
    }
    __syncthreads();
  }

  // epilogue: C/D layout col=lane&15, row=(lane>>4)*4+i
#pragma unroll
  for (int cb = 0; cb < 4; ++cb) {
    int colg = colblk + wc + cb * 16 + lr;
    float badd = BIAS ? bias[colg] : 0.0f;
#pragma unroll
    for (int rb = 0; rb < 4; ++rb) {
#pragma unroll
      for (int i = 0; i < 4; ++i) {
        int row = rowblk + wr + rb * 16 + lk * 4 + i;
        float v = acc[rb][cb][i] + badd;
        if (RELU) v = fmaxf(v, 0.f);
        C[(size_t)row * N + colg] = f2bf(v);
      }
    }
  }
}

// ---------------- aggregation: out[i] = sum_e val[e]*xw[col[e]] + dinv^2*xw[i] ----

template <int PT, bool INF32>
__device__ __forceinline__ void load_row(const void* p, size_t off, float* xv) {
  if (INF32) {
    if (PT == 2) {
      float2 f = *(const float2*)((const float*)p + off);
      xv[0] = f.x; xv[1] = f.y;
    } else {
      float4 f0 = *(const float4*)((const float*)p + off);
      float4 f1 = *(const float4*)((const float*)p + off + 4);
      xv[0] = f0.x; xv[1] = f0.y; xv[2] = f0.z; xv[3] = f0.w;
      xv[4] = f1.x; xv[5] = f1.y; xv[6] = f1.z; xv[7] = f1.w;
    }
  } else {
    if (PT == 2) {
      unsigned int u = *(const unsigned int*)((const unsigned short*)p + off);
      xv[0] = bf2f((unsigned short)(u & 0xffffu));
      xv[1] = bf2f((unsigned short)(u >> 16));
    } else {
      bf16x8 r = *(const bf16x8*)((const short*)p + off);
#pragma unroll
      for (int j = 0; j < 8; ++j) xv[j] = bf2f((unsigned short)r[j]);
    }
  }
}

template <int PT, bool INF32, bool BIAS, bool RELU, bool W32, bool W16>
__global__ __launch_bounds__(256) void agg_kernel(
    const void* __restrict__ xw, const int* __restrict__ col, const float* __restrict__ val,
    const int* __restrict__ rowPtr, const float* __restrict__ dinv,
    const float* __restrict__ bias, float* __restrict__ out32,
    unsigned short* __restrict__ out16, int n) {
  const int DIM = PT * 64;
  int node = blockIdx.x * 4 + (threadIdx.x >> 6);
  if (node >= n) return;
  int t = threadIdx.x & 63;
  float acc[PT];
#pragma unroll
  for (int q = 0; q < PT; ++q) acc[q] = 0.f;

  int beg = rowPtr[node], end = rowPtr[node + 1];
  int e = beg;
  for (; e + 4 <= end; e += 4) {
    int s0 = col[e + 0], s1 = col[e + 1], s2 = col[e + 2], s3 = col[e + 3];
    float v0 = val[e + 0], v1 = val[e + 1], v2 = val[e + 2], v3 = val[e + 3];
    float x0[PT], x1[PT], x2[PT], x3[PT];
    load_row<PT, INF32>(xw, (size_t)s0 * DIM + t * PT, x0);
    load_row<PT, INF32>(xw, (size_t)s1 * DIM + t * PT, x1);
    load_row<PT, INF32>(xw, (size_t)s2 * DIM + t * PT, x2);
    load_row<PT, INF32>(xw, (size_t)s3 * DIM + t * PT, x3);
#pragma unroll
    for (int q = 0; q < PT; ++q)
      acc[q] += v0 * x0[q] + v1 * x1[q] + v2 * x2[q] + v3 * x3[q];
  }
  for (; e < end; ++e) {
    int s = col[e];
    float v = val[e];
    float xv[PT];
    load_row<PT, INF32>(xw, (size_t)s * DIM + t * PT, xv);
#pragma unroll
    for (int q = 0; q < PT; ++q) acc[q] += v * xv[q];
  }
  float di = dinv[node];
  float sl = di * di;
  {
    float xv[PT];
    load_row<PT, INF32>(xw, (size_t)node * DIM + t * PT, xv);
#pragma unroll
    for (int q = 0; q < PT; ++q) acc[q] += sl * xv[q];
  }
  if (BIAS) {
#pragma unroll
    for (int q = 0; q < PT; ++q) acc[q] += bias[t * PT + q];
  }
  if (RELU) {
#pragma unroll
    for (int q = 0; q < PT; ++q) acc[q] = fmaxf(acc[q], 0.f);
  }
  if (W32) {
    if (PT == 2) {
      float2 o; o.x = acc[0]; o.y = acc[1];
      *(float2*)(out32 + (size_t)node * DIM + t * PT) = o;
    } else {
      float4 o0, o1;
      o0.x = acc[0]; o0.y = acc[1]; o0.z = acc[2]; o0.w = acc[3];
      o1.x = acc[4 % PT]; o1.y = acc[5 % PT]; o1.z = acc[6 % PT]; o1.w = acc[7 % PT];
      *(float4*)(out32 + (size_t)node * DIM + t * PT) = o0;
      *(float4*)(out32 + (size_t)node * DIM + t * PT + 4) = o1;
    }
  }
  if (W16) {
    if (PT == 2) {
      unsigned int u = (unsigned int)f2bf(acc[0]) | ((unsigned int)f2bf(acc[1]) << 16);
      *(unsigned int*)(out16 + (size_t)node * DIM + t * PT) = u;
    } else {
      bf16x8 o;
#pragma unroll
      for (int j = 0; j < PT; ++j) o[j % 8] = (short)f2bf(acc[j]);
      *(bf16x8*)(out16 + (size_t)node * DIM + t * PT) = o;
    }
  }
}

// ---------------------------------------------------------------------------

extern "C" void kernel_launch(void* const* d_in, const int* in_sizes, int n_in,
                              void* d_out, int out_size, void* d_ws, size_t ws_size,
                              hipStream_t stream) {
  const float* x  = (const float*)d_in[0];
  const int*   ei = (const int*)d_in[1];
  const float* ew = (const float*)d_in[2];
  const float* W1 = (const float*)d_in[3];
  const float* b1 = (const float*)d_in[4];
  const float* W2 = (const float*)d_in[5];
  const float* b2 = (const float*)d_in[6];
  const float* W3 = (const float*)d_in[7];
  const float* b3 = (const float*)d_in[8];
  const float* W4 = (const float*)d_in[9];
  const float* b4 = (const float*)d_in[10];

  const int n = in_sizes[0] / 512;         // 50000
  const int E = in_sizes[2];               // 800000
  const int MB128 = (n + 127) / 128;       // 391
  const int Mpad = MB128 * 128;            // 50048

  float* out   = (float*)d_out;
  float* z_out = out + (size_t)n * 512;

  // ---- workspace layout (~124 MB) ----
  char* w = (char*)d_ws;
  auto alloc = [&](size_t bytes) {
    char* p = w;
    w += (bytes + 255) & ~(size_t)255;
    return p;
  };
  float* deg    = (float*)alloc((size_t)n * 4);
  float* dinv   = (float*)alloc((size_t)n * 4);
  int*   cnt    = (int*)alloc((size_t)n * 4);
  int*   rowPtr = (int*)alloc((size_t)(n + 1) * 4);
  int*   fill   = (int*)alloc((size_t)n * 4);
  int*   sums   = (int*)alloc(4096);
  int*   col    = (int*)alloc((size_t)E * 4);
  float* val    = (float*)alloc((size_t)E * 4);
  short* whi1 = (short*)alloc((size_t)512 * 512 * 2);
  short* whi2 = (short*)alloc((size_t)512 * 128 * 2);
  short* whi3 = (short*)alloc((size_t)128 * 512 * 2);
  short* whi4 = (short*)alloc((size_t)512 * 512 * 2);
  unsigned short* T  = (unsigned short*)alloc((size_t)Mpad * 128 * 2);  // xw2 / aggz
  unsigned short* B1 = (unsigned short*)alloc((size_t)Mpad * 512 * 2);  // xbf / h / xw4
  unsigned short* B2 = (unsigned short*)alloc((size_t)Mpad * 512 * 2);  // xw1 / zbf / h2

  unsigned short* zbf = B2;  // [n,128] bf16, alive between L2 agg and L3 agg

  const int* srcp = ei;
  const int* dstp = ei + E;

  // ---- graph preprocessing ----
  hipMemsetAsync(deg, 0, (size_t)n * 4, stream);
  hipMemsetAsync(cnt, 0, (size_t)n * 4, stream);
  deg_hist_kernel<<<(E + 255) / 256, 256, 0, stream>>>(dstp, ew, deg, cnt, E);
  dinv_kernel<<<(n + 255) / 256, 256, 0, stream>>>(deg, dinv, n);
  int NB = (n + 511) / 512;
  block_sums_kernel<<<NB, 512, 0, stream>>>(cnt, sums, n);
  scan_sums_kernel<<<1, 64, 0, stream>>>(sums, NB);
  scan_final_kernel<<<NB, 512, 0, stream>>>(cnt, sums, rowPtr, fill, n);
  scatter_edges_kernel<<<(E + 255) / 256, 256, 0, stream>>>(srcp, dstp, ew, dinv, fill, col, val, E);

  // ---- weight tiling + x conversion ----
  tile_w_kernel<<<(4 * 8 * 1024 + 255) / 256, 256, 0, stream>>>(W1, whi1, 512, 512);
  tile_w_kernel<<<(1 * 8 * 1024 + 255) / 256, 256, 0, stream>>>(W2, whi2, 512, 128);
  tile_w_kernel<<<(4 * 2 * 1024 + 255) / 256, 256, 0, stream>>>(W3, whi3, 128, 512);
  tile_w_kernel<<<(4 * 8 * 1024 + 255) / 256, 256, 0, stream>>>(W4, whi4, 512, 512);
  cvt_x_kernel<<<(Mpad * 64 + 255) / 256, 256, 0, stream>>>(x, B1, n, Mpad);

  const int AGB = (n + 3) / 4;  // 12500

  // ---- layer 1: xw1 = xbf@W1 -> B2 ; h = relu(N.xw1 + b1) -> B1 ----
  mfma_gemm<false, false><<<dim3(4, MB128), 256, 0, stream>>>(B1, whi1, nullptr, B2, 512, 512);
  agg_kernel<8, false, true, true, false, true><<<AGB, 256, 0, stream>>>(
      B2, col, val, rowPtr, dinv, b1, nullptr, B1, n);

  // ---- layer 2: xw2 = h@W2 -> T ; z = N.xw2 + b2 -> z_out (fp32) + zbf (bf16) ----
  mfma_gemm<false, false><<<dim3(1, MB128), 256, 0, stream>>>(B1, whi2, nullptr, T, 128, 512);
  agg_kernel<2, false, true, false, true, true><<<AGB, 256, 0, stream>>>(
      T, col, val, rowPtr, dinv, b2, z_out, zbf, n);

  // ---- layer 3: aggz = N.z (bf16 gather) -> T ; h2 = relu(aggz@W3 + b3) -> B2 ----
  agg_kernel<2, false, false, false, false, true><<<AGB, 256, 0, stream>>>(
      zbf, col, val, rowPtr, dinv, nullptr, nullptr, T, n);
  mfma_gemm<true, true><<<dim3(4, MB128), 256, 0, stream>>>(T, whi3, b3, B2, 512, 128);

  // ---- layer 4: xw4 = h2@W4 -> B1 ; x_recon = N.xw4 + b4 -> out (fp32) ----
  mfma_gemm<false, false><<<dim3(4, MB128), 256, 0, stream>>>(B2, whi4, nullptr, B1, 512, 512);
  agg_kernel<8, false, true, false, true, false><<<AGB, 256, 0, stream>>>(
      B1, col, val, rowPtr, dinv, b4, out, nullptr, n);
}

// Round 5
// 640.807 us; speedup vs baseline: 2.6767x; 1.0422x over previous
//
#include <hip/hip_runtime.h>

// ---------------------------------------------------------------------------
// GCN autoencoder, LDS-staged bf16-MFMA edition.
//   GEMMs: mfma_f32_16x16x32_bf16, 128xBN tile (BN=256 for N>=256, halves A
//          re-reads vs 128x128), BK=64, global_load_lds staging with
//          source-side XOR swizzle (rule #21: linear LDS dest, inverse-
//          swizzled global source, swizzled ds_read).
//   Weights pure bf16. Aggregation: CSR gather-sum over bf16 rows,
//   4-edge unrolled, packed (col,val) int2 payload.
// ---------------------------------------------------------------------------

typedef short bf16x8 __attribute__((ext_vector_type(8)));
typedef float f32x4 __attribute__((ext_vector_type(4)));

__device__ __forceinline__ float bf2f(unsigned short u) {
  return __uint_as_float(((unsigned int)u) << 16);
}
__device__ __forceinline__ unsigned short f2bf(float f) {
  unsigned int u = __float_as_uint(f);
  return (unsigned short)((u + 0x7fffu + ((u >> 16) & 1u)) >> 16);  // RNE
}

__device__ __forceinline__ void gload_lds16(const void* g, void* l) {
  __builtin_amdgcn_global_load_lds(
      (const __attribute__((address_space(1))) unsigned int*)g,
      (__attribute__((address_space(3))) unsigned int*)l, 16, 0, 0);
}

// ---------------- graph preprocessing (CSR by dst) ----------------

__global__ void deg_hist_kernel(const int* __restrict__ dst, const float* __restrict__ ew,
                                float* __restrict__ deg, int* __restrict__ cnt, int E) {
  int e = blockIdx.x * blockDim.x + threadIdx.x;
  if (e >= E) return;
  int d = dst[e];
  atomicAdd(&deg[d], ew[e]);
  atomicAdd(&cnt[d], 1);
}

__global__ void dinv_kernel(const float* __restrict__ deg, float* __restrict__ dinv, int n) {
  int i = blockIdx.x * blockDim.x + threadIdx.x;
  if (i >= n) return;
  dinv[i] = rsqrtf(deg[i] + 1.0f);
}

__global__ void block_sums_kernel(const int* __restrict__ cnt, int* __restrict__ sums, int n) {
  __shared__ int sh[512];
  int i = blockIdx.x * 512 + threadIdx.x;
  sh[threadIdx.x] = (i < n) ? cnt[i] : 0;
  __syncthreads();
  for (int s = 256; s > 0; s >>= 1) {
    if (threadIdx.x < s) sh[threadIdx.x] += sh[threadIdx.x + s];
    __syncthreads();
  }
  if (threadIdx.x == 0) sums[blockIdx.x] = sh[0];
}

__global__ void scan_sums_kernel(int* sums, int nb) {
  if (threadIdx.x == 0 && blockIdx.x == 0) {
    int acc = 0;
    for (int i = 0; i < nb; ++i) { int v = sums[i]; sums[i] = acc; acc += v; }
  }
}

__global__ void scan_final_kernel(const int* __restrict__ cnt, const int* __restrict__ sums,
                                  int* __restrict__ rowPtr, int* __restrict__ fill, int n) {
  __shared__ int sh[512];
  int i = blockIdx.x * 512 + threadIdx.x;
  int v = (i < n) ? cnt[i] : 0;
  sh[threadIdx.x] = v;
  __syncthreads();
  for (int off = 1; off < 512; off <<= 1) {
    int y = (threadIdx.x >= off) ? sh[threadIdx.x - off] : 0;
    __syncthreads();
    sh[threadIdx.x] += y;
    __syncthreads();
  }
  if (i < n) {
    int incl = sh[threadIdx.x];
    int base = sums[blockIdx.x];
    int excl = base + incl - v;
    rowPtr[i] = excl;
    fill[i] = excl;
    if (i == n - 1) rowPtr[n] = base + incl;
  }
}

__global__ void scatter_edges_kernel(const int* __restrict__ src, const int* __restrict__ dst,
                                     const float* __restrict__ ew, const float* __restrict__ dinv,
                                     int* __restrict__ fill, int2* __restrict__ pk, int E) {
  int e = blockIdx.x * blockDim.x + threadIdx.x;
  if (e >= E) return;
  int s = src[e], d = dst[e];
  int p = atomicAdd(&fill[d], 1);
  float v = dinv[s] * ew[e] * dinv[d];
  pk[p] = make_int2(s, __float_as_int(v));
}

// ---------------- x -> bf16 (pad rows zeroed) ----------------

__global__ void cvt_x_kernel(const float* __restrict__ x, unsigned short* __restrict__ xbf,
                             int n, int Mpad) {
  int g = blockIdx.x * 256 + threadIdx.x;
  int total = Mpad * 64;
  if (g >= total) return;
  int row = g >> 6;
  int cc = (g & 63) << 3;
  bf16x8 o;
  if (row < n) {
    const float* p = x + (size_t)row * 512 + cc;
    float4 f0 = *(const float4*)p;
    float4 f1 = *(const float4*)(p + 4);
    o[0] = (short)f2bf(f0.x); o[1] = (short)f2bf(f0.y);
    o[2] = (short)f2bf(f0.z); o[3] = (short)f2bf(f0.w);
    o[4] = (short)f2bf(f1.x); o[5] = (short)f2bf(f1.y);
    o[6] = (short)f2bf(f1.z); o[7] = (short)f2bf(f1.w);
  } else {
#pragma unroll
    for (int j = 0; j < 8; ++j) o[j] = 0;
  }
  *(bf16x8*)(xbf + (size_t)g * 8) = o;
}

// ---------------- weight bf16 convert, swizzled 128-col tile layout --------
// Per (nb, kb): 1024 16B chunks. Chunk c: col = c>>3 (0..127), stored k-chunk
// kcs = c&7 holds global k-chunk (kcs ^ (col&7)) — the LDS image directly.

__global__ void tile_w_kernel(const float* __restrict__ W, short* __restrict__ hi,
                              int K, int N) {
  int g = blockIdx.x * 256 + threadIdx.x;
  int kb_cnt = K >> 6;
  int total = (N >> 7) * kb_cnt * 1024;
  if (g >= total) return;
  int c = g & 1023;
  int t = g >> 10;
  int kb = t % kb_cnt;
  int nb = t / kb_cnt;
  int colg = (nb << 7) + (c >> 3);
  int k0 = (kb << 6) + (((c & 7) ^ ((c >> 3) & 7)) << 3);
  bf16x8 h8;
#pragma unroll
  for (int j = 0; j < 8; ++j) {
    float w = W[(size_t)(k0 + j) * N + colg];
    h8[j] = (short)f2bf(w);
  }
  *(bf16x8*)(hi + (size_t)g * 8) = h8;
}

// ---------------- MFMA GEMM (LDS-staged): C[Mpad,N] bf16 = A * B ----------
// BM=128, BN in {128,256}, BK=64. Threads = 2*BN (4 or 8 waves), wave tile
// 64x64. grid (N/BN, Mpad/128).

template <int BN, bool BIAS, bool RELU>
__global__ __launch_bounds__(2 * BN) void mfma_gemm(
    const unsigned short* __restrict__ A, const short* __restrict__ Bhi,
    const float* __restrict__ bias, unsigned short* __restrict__ C, int N, int K) {
  constexpr int W = BN / 32;       // waves: 4 or 8
  constexpr int RW = 128 / W;      // A rows per wave: 32 or 16
  constexpr int IA = RW / 8;       // A gload issues per thread: 4 or 2
  constexpr int NH = BN / 128;     // 128-col halves: 1 or 2
  constexpr int WH = W / NH;       // waves per half: 4
  constexpr int CW = BN / 64;      // wave cols: 2 or 4

  __shared__ short As[8192];       // [128 rows][8 kc][8] swizzled image
  __shared__ short Bs[BN * 64];    // [BN cols][8 kc][8]

  const int tid = threadIdx.x;
  const int lane = tid & 63;
  const int wave = tid >> 6;
  const int rowblk = blockIdx.y << 7;
  const int colblk = blockIdx.x * BN;
  const int wr = (wave / CW) << 6;
  const int wc = (wave % CW) << 6;
  const int lr = lane & 15;
  const int lk = lane >> 4;
  const int kbN = K >> 6;
  const int half = wave / WH;
  const int wh = wave % WH;
  const int nb0 = colblk >> 7;

  f32x4 acc[4][4];
#pragma unroll
  for (int i = 0; i < 4; ++i)
#pragma unroll
    for (int j = 0; j < 4; ++j) {
      f32x4 z = {0.f, 0.f, 0.f, 0.f};
      acc[i][j] = z;
    }

  // A staging: wave covers rows [wave*RW, wave*RW+RW); issue i covers 8 rows.
  // LDS dest linear (base+lane*16); source k-chunk pre-swizzled:
  // row&7 == lane>>3 (issue offset is a multiple of 8 rows).
  const int arow = wave * RW + (lane >> 3);
  const size_t abase = (size_t)(rowblk + arow) * K + (size_t)(((lane & 7) ^ ((lane >> 3) & 7)) << 3);
  short* AsW = As + wave * (RW * 64);
  short* BsW = Bs + half * 8192 + wh * 2048;

  for (int kb = 0; kb < kbN; ++kb) {
    const unsigned short* asrc = A + abase + (kb << 6);
    const short* bsrc = Bhi + ((size_t)(nb0 + half) * kbN + kb) * 8192 + (size_t)(wh * 256 + lane) * 8;
#pragma unroll
    for (int i = 0; i < IA; ++i)
      gload_lds16(asrc + (size_t)(i * 8) * K, AsW + i * 512);
#pragma unroll
    for (int i = 0; i < 4; ++i)
      gload_lds16(bsrc + i * 512, BsW + i * 512);
    __syncthreads();
#pragma unroll
    for (int kk = 0; kk < 2; ++kk) {
      bf16x8 af[4], bhf[4];
      const int kc = kk * 4 + lk;
#pragma unroll
      for (int rb = 0; rb < 4; ++rb) {
        int rowl = wr + rb * 16 + lr;
        af[rb] = *(const bf16x8*)(As + rowl * 64 + ((kc ^ (rowl & 7)) << 3));
      }
#pragma unroll
      for (int cb = 0; cb < 4; ++cb) {
        int coll = wc + cb * 16 + lr;
        bhf[cb] = *(const bf16x8*)(Bs + coll * 64 + ((kc ^ (coll & 7)) << 3));
      }
#pragma unroll
      for (int rb = 0; rb < 4; ++rb)
#pragma unroll
        for (int cb = 0; cb < 4; ++cb)
          acc[rb][cb] = __builtin_amdgcn_mfma_f32_16x16x32_bf16(af[rb], bhf[cb], acc[rb][cb], 0, 0, 0);
    }
    __syncthreads();
  }

  // epilogue: C/D layout col=lane&15, row=(lane>>4)*4+i
#pragma unroll
  for (int cb = 0; cb < 4; ++cb) {
    int colg = colblk + wc + cb * 16 + lr;
    float badd = BIAS ? bias[colg] : 0.0f;
#pragma unroll
    for (int rb = 0; rb < 4; ++rb) {
#pragma unroll
      for (int i = 0; i < 4; ++i) {
        int row = rowblk + wr + rb * 16 + lk * 4 + i;
        float v = acc[rb][cb][i] + badd;
        if (RELU) v = fmaxf(v, 0.f);
        C[(size_t)row * N + colg] = f2bf(v);
      }
    }
  }
}

// ---------------- aggregation: out[i] = sum_e val[e]*xw[col[e]] + dinv^2*xw[i] ----

template <int PT, bool INF32>
__device__ __forceinline__ void load_row(const void* p, size_t off, float* xv) {
  if (INF32) {
    if (PT == 2) {
      float2 f = *(const float2*)((const float*)p + off);
      xv[0] = f.x; xv[1] = f.y;
    } else {
      float4 f0 = *(const float4*)((const float*)p + off);
      float4 f1 = *(const float4*)((const float*)p + off + 4);
      xv[0] = f0.x; xv[1] = f0.y; xv[2] = f0.z; xv[3] = f0.w;
      xv[4] = f1.x; xv[5] = f1.y; xv[6] = f1.z; xv[7] = f1.w;
    }
  } else {
    if (PT == 2) {
      unsigned int u = *(const unsigned int*)((const unsigned short*)p + off);
      xv[0] = bf2f((unsigned short)(u & 0xffffu));
      xv[1] = bf2f((unsigned short)(u >> 16));
    } else {
      bf16x8 r = *(const bf16x8*)((const short*)p + off);
#pragma unroll
      for (int j = 0; j < 8; ++j) xv[j] = bf2f((unsigned short)r[j]);
    }
  }
}

template <int PT, bool INF32, bool BIAS, bool RELU, bool W32, bool W16>
__global__ __launch_bounds__(256) void agg_kernel(
    const void* __restrict__ xw, const int2* __restrict__ pk,
    const int* __restrict__ rowPtr, const float* __restrict__ dinv,
    const float* __restrict__ bias, float* __restrict__ out32,
    unsigned short* __restrict__ out16, int n) {
  const int DIM = PT * 64;
  int node = blockIdx.x * 4 + (threadIdx.x >> 6);
  if (node >= n) return;
  int t = threadIdx.x & 63;
  float acc[PT];
#pragma unroll
  for (int q = 0; q < PT; ++q) acc[q] = 0.f;

  int beg = rowPtr[node], end = rowPtr[node + 1];
  int e = beg;
  for (; e + 4 <= end; e += 4) {
    int2 p0 = pk[e + 0], p1 = pk[e + 1], p2 = pk[e + 2], p3 = pk[e + 3];
    float x0[PT], x1[PT], x2[PT], x3[PT];
    load_row<PT, INF32>(xw, (size_t)p0.x * DIM + t * PT, x0);
    load_row<PT, INF32>(xw, (size_t)p1.x * DIM + t * PT, x1);
    load_row<PT, INF32>(xw, (size_t)p2.x * DIM + t * PT, x2);
    load_row<PT, INF32>(xw, (size_t)p3.x * DIM + t * PT, x3);
    float v0 = __int_as_float(p0.y), v1 = __int_as_float(p1.y);
    float v2 = __int_as_float(p2.y), v3 = __int_as_float(p3.y);
#pragma unroll
    for (int q = 0; q < PT; ++q)
      acc[q] += v0 * x0[q] + v1 * x1[q] + v2 * x2[q] + v3 * x3[q];
  }
  for (; e < end; ++e) {
    int2 pe = pk[e];
    float v = __int_as_float(pe.y);
    float xv[PT];
    load_row<PT, INF32>(xw, (size_t)pe.x * DIM + t * PT, xv);
#pragma unroll
    for (int q = 0; q < PT; ++q) acc[q] += v * xv[q];
  }
  float di = dinv[node];
  float sl = di * di;
  {
    float xv[PT];
    load_row<PT, INF32>(xw, (size_t)node * DIM + t * PT, xv);
#pragma unroll
    for (int q = 0; q < PT; ++q) acc[q] += sl * xv[q];
  }
  if (BIAS) {
#pragma unroll
    for (int q = 0; q < PT; ++q) acc[q] += bias[t * PT + q];
  }
  if (RELU) {
#pragma unroll
    for (int q = 0; q < PT; ++q) acc[q] = fmaxf(acc[q], 0.f);
  }
  if (W32) {
    if (PT == 2) {
      float2 o; o.x = acc[0]; o.y = acc[1];
      *(float2*)(out32 + (size_t)node * DIM + t * PT) = o;
    } else {
      float4 o0, o1;
      o0.x = acc[0]; o0.y = acc[1]; o0.z = acc[2]; o0.w = acc[3];
      o1.x = acc[4 % PT]; o1.y = acc[5 % PT]; o1.z = acc[6 % PT]; o1.w = acc[7 % PT];
      *(float4*)(out32 + (size_t)node * DIM + t * PT) = o0;
      *(float4*)(out32 + (size_t)node * DIM + t * PT + 4) = o1;
    }
  }
  if (W16) {
    if (PT == 2) {
      unsigned int u = (unsigned int)f2bf(acc[0]) | ((unsigned int)f2bf(acc[1]) << 16);
      *(unsigned int*)(out16 + (size_t)node * DIM + t * PT) = u;
    } else {
      bf16x8 o;
#pragma unroll
      for (int j = 0; j < PT; ++j) o[j % 8] = (short)f2bf(acc[j]);
      *(bf16x8*)(out16 + (size_t)node * DIM + t * PT) = o;
    }
  }
}

// ---------------------------------------------------------------------------

extern "C" void kernel_launch(void* const* d_in, const int* in_sizes, int n_in,
                              void* d_out, int out_size, void* d_ws, size_t ws_size,
                              hipStream_t stream) {
  const float* x  = (const float*)d_in[0];
  const int*   ei = (const int*)d_in[1];
  const float* ew = (const float*)d_in[2];
  const float* W1 = (const float*)d_in[3];
  const float* b1 = (const float*)d_in[4];
  const float* W2 = (const float*)d_in[5];
  const float* b2 = (const float*)d_in[6];
  const float* W3 = (const float*)d_in[7];
  const float* b3 = (const float*)d_in[8];
  const float* W4 = (const float*)d_in[9];
  const float* b4 = (const float*)d_in[10];

  const int n = in_sizes[0] / 512;         // 50000
  const int E = in_sizes[2];               // 800000
  const int MB128 = (n + 127) / 128;       // 391
  const int Mpad = MB128 * 128;            // 50048

  float* out   = (float*)d_out;
  float* z_out = out + (size_t)n * 512;

  // ---- workspace layout (~127 MB) ----
  char* w = (char*)d_ws;
  auto alloc = [&](size_t bytes) {
    char* p = w;
    w += (bytes + 255) & ~(size_t)255;
    return p;
  };
  float* deg    = (float*)alloc((size_t)n * 4);
  float* dinv   = (float*)alloc((size_t)n * 4);
  int*   cnt    = (int*)alloc((size_t)n * 4);
  int*   rowPtr = (int*)alloc((size_t)(n + 1) * 4);
  int*   fill   = (int*)alloc((size_t)n * 4);
  int*   sums   = (int*)alloc(4096);
  int2*  pk     = (int2*)alloc((size_t)E * 8);
  short* whi1 = (short*)alloc((size_t)512 * 512 * 2);
  short* whi2 = (short*)alloc((size_t)512 * 128 * 2);
  short* whi3 = (short*)alloc((size_t)128 * 512 * 2);
  short* whi4 = (short*)alloc((size_t)512 * 512 * 2);
  unsigned short* T  = (unsigned short*)alloc((size_t)Mpad * 128 * 2);  // xw2 / aggz
  unsigned short* B1 = (unsigned short*)alloc((size_t)Mpad * 512 * 2);  // xbf / h / xw4
  unsigned short* B2 = (unsigned short*)alloc((size_t)Mpad * 512 * 2);  // xw1 / zbf / h2

  unsigned short* zbf = B2;  // [n,128] bf16, alive between L2 agg and L3 agg

  const int* srcp = ei;
  const int* dstp = ei + E;

  // ---- graph preprocessing ----
  hipMemsetAsync(deg, 0, (size_t)n * 4, stream);
  hipMemsetAsync(cnt, 0, (size_t)n * 4, stream);
  deg_hist_kernel<<<(E + 255) / 256, 256, 0, stream>>>(dstp, ew, deg, cnt, E);
  dinv_kernel<<<(n + 255) / 256, 256, 0, stream>>>(deg, dinv, n);
  int NB = (n + 511) / 512;
  block_sums_kernel<<<NB, 512, 0, stream>>>(cnt, sums, n);
  scan_sums_kernel<<<1, 64, 0, stream>>>(sums, NB);
  scan_final_kernel<<<NB, 512, 0, stream>>>(cnt, sums, rowPtr, fill, n);
  scatter_edges_kernel<<<(E + 255) / 256, 256, 0, stream>>>(srcp, dstp, ew, dinv, fill, pk, E);

  // ---- weight tiling + x conversion ----
  tile_w_kernel<<<(4 * 8 * 1024 + 255) / 256, 256, 0, stream>>>(W1, whi1, 512, 512);
  tile_w_kernel<<<(1 * 8 * 1024 + 255) / 256, 256, 0, stream>>>(W2, whi2, 512, 128);
  tile_w_kernel<<<(4 * 2 * 1024 + 255) / 256, 256, 0, stream>>>(W3, whi3, 128, 512);
  tile_w_kernel<<<(4 * 8 * 1024 + 255) / 256, 256, 0, stream>>>(W4, whi4, 512, 512);
  cvt_x_kernel<<<(Mpad * 64 + 255) / 256, 256, 0, stream>>>(x, B1, n, Mpad);

  const int AGB = (n + 3) / 4;  // 12500

  // ---- layer 1: xw1 = xbf@W1 -> B2 ; h = relu(N.xw1 + b1) -> B1 ----
  mfma_gemm<256, false, false><<<dim3(2, MB128), 512, 0, stream>>>(B1, whi1, nullptr, B2, 512, 512);
  agg_kernel<8, false, true, true, false, true><<<AGB, 256, 0, stream>>>(
      B2, pk, rowPtr, dinv, b1, nullptr, B1, n);

  // ---- layer 2: xw2 = h@W2 -> T ; z = N.xw2 + b2 -> z_out (fp32) + zbf (bf16) ----
  mfma_gemm<128, false, false><<<dim3(1, MB128), 256, 0, stream>>>(B1, whi2, nullptr, T, 128, 512);
  agg_kernel<2, false, true, false, true, true><<<AGB, 256, 0, stream>>>(
      T, pk, rowPtr, dinv, b2, z_out, zbf, n);

  // ---- layer 3: aggz = N.z (bf16 gather) -> T ; h2 = relu(aggz@W3 + b3) -> B2 ----
  agg_kernel<2, false, false, false, false, true><<<AGB, 256, 0, stream>>>(
      zbf, pk, rowPtr, dinv, nullptr, nullptr, T, n);
  mfma_gemm<256, true, true><<<dim3(2, MB128), 512, 0, stream>>>(T, whi3, b3, B2, 512, 128);

  // ---- layer 4: xw4 = h2@W4 -> B1 ; x_recon = N.xw4 + b4 -> out (fp32) ----
  mfma_gemm<256, false, false><<<dim3(2, MB128), 512, 0, stream>>>(B2, whi4, nullptr, B1, 512, 512);
  agg_kernel<8, false, true, false, true, false><<<AGB, 256, 0, stream>>>(
      B1, pk, rowPtr, dinv, b4, out, nullptr, n);
}

// Round 6
// 617.192 us; speedup vs baseline: 2.7792x; 1.0383x over previous
//
#include <hip/hip_runtime.h>

// ---------------------------------------------------------------------------
// GCN autoencoder, LDS-staged bf16-MFMA edition.
//   GEMMs: mfma_f32_16x16x32_bf16, 128xBN tile (BN=256 for N>=256), BK=64,
//          global_load_lds staging with source-side XOR swizzle (rule #21);
//          GEMM1 reg-stages fp32 x directly (cvt in regs, swizzled ds_write).
//   Weights pure bf16. Aggregation: CSR gather-sum over bf16 rows,
//   UF-edge unrolled (UF=8 for cache-resident 128-dim, 4 for 512-dim).
// ---------------------------------------------------------------------------

typedef short bf16x8 __attribute__((ext_vector_type(8)));
typedef float f32x4 __attribute__((ext_vector_type(4)));

__device__ __forceinline__ float bf2f(unsigned short u) {
  return __uint_as_float(((unsigned int)u) << 16);
}
__device__ __forceinline__ unsigned short f2bf(float f) {
  unsigned int u = __float_as_uint(f);
  return (unsigned short)((u + 0x7fffu + ((u >> 16) & 1u)) >> 16);  // RNE
}

__device__ __forceinline__ void gload_lds16(const void* g, void* l) {
  __builtin_amdgcn_global_load_lds(
      (const __attribute__((address_space(1))) unsigned int*)g,
      (__attribute__((address_space(3))) unsigned int*)l, 16, 0, 0);
}

// ---------------- graph preprocessing (CSR by dst) ----------------

__global__ void deg_hist_kernel(const int* __restrict__ dst, const float* __restrict__ ew,
                                float* __restrict__ deg, int* __restrict__ cnt, int E) {
  int e = blockIdx.x * blockDim.x + threadIdx.x;
  if (e >= E) return;
  int d = dst[e];
  atomicAdd(&deg[d], ew[e]);
  atomicAdd(&cnt[d], 1);
}

__global__ void dinv_kernel(const float* __restrict__ deg, float* __restrict__ dinv, int n) {
  int i = blockIdx.x * blockDim.x + threadIdx.x;
  if (i >= n) return;
  dinv[i] = rsqrtf(deg[i] + 1.0f);
}

__global__ void block_sums_kernel(const int* __restrict__ cnt, int* __restrict__ sums, int n) {
  __shared__ int sh[512];
  int i = blockIdx.x * 512 + threadIdx.x;
  sh[threadIdx.x] = (i < n) ? cnt[i] : 0;
  __syncthreads();
  for (int s = 256; s > 0; s >>= 1) {
    if (threadIdx.x < s) sh[threadIdx.x] += sh[threadIdx.x + s];
    __syncthreads();
  }
  if (threadIdx.x == 0) sums[blockIdx.x] = sh[0];
}

// single-block exclusive scan of block sums (nb <= 512)
__global__ void scan_sums_kernel(int* sums, int nb) {
  __shared__ int sh[512];
  int t = threadIdx.x;
  int v = (t < nb) ? sums[t] : 0;
  sh[t] = v;
  __syncthreads();
  for (int off = 1; off < 512; off <<= 1) {
    int y = (t >= off) ? sh[t - off] : 0;
    __syncthreads();
    sh[t] += y;
    __syncthreads();
  }
  if (t < nb) sums[t] = sh[t] - v;  // exclusive
}

__global__ void scan_final_kernel(const int* __restrict__ cnt, const int* __restrict__ sums,
                                  int* __restrict__ rowPtr, int* __restrict__ fill, int n) {
  __shared__ int sh[512];
  int i = blockIdx.x * 512 + threadIdx.x;
  int v = (i < n) ? cnt[i] : 0;
  sh[threadIdx.x] = v;
  __syncthreads();
  for (int off = 1; off < 512; off <<= 1) {
    int y = (threadIdx.x >= off) ? sh[threadIdx.x - off] : 0;
    __syncthreads();
    sh[threadIdx.x] += y;
    __syncthreads();
  }
  if (i < n) {
    int incl = sh[threadIdx.x];
    int base = sums[blockIdx.x];
    int excl = base + incl - v;
    rowPtr[i] = excl;
    fill[i] = excl;
    if (i == n - 1) rowPtr[n] = base + incl;
  }
}

__global__ void scatter_edges_kernel(const int* __restrict__ src, const int* __restrict__ dst,
                                     const float* __restrict__ ew, const float* __restrict__ dinv,
                                     int* __restrict__ fill, int2* __restrict__ pk, int E) {
  int e = blockIdx.x * blockDim.x + threadIdx.x;
  if (e >= E) return;
  int s = src[e], d = dst[e];
  int p = atomicAdd(&fill[d], 1);
  float v = dinv[s] * ew[e] * dinv[d];
  pk[p] = make_int2(s, __float_as_int(v));
}

// ---------------- weight bf16 convert, swizzled 128-col tile layout --------
// Per (nb, kb): 1024 16B chunks. Chunk c: col = c>>3 (0..127), stored k-chunk
// kcs = c&7 holds global k-chunk (kcs ^ (col&7)) — the LDS image directly.

__global__ void tile_w_kernel(const float* __restrict__ W, short* __restrict__ hi,
                              int K, int N) {
  int g = blockIdx.x * 256 + threadIdx.x;
  int kb_cnt = K >> 6;
  int total = (N >> 7) * kb_cnt * 1024;
  if (g >= total) return;
  int c = g & 1023;
  int t = g >> 10;
  int kb = t % kb_cnt;
  int nb = t / kb_cnt;
  int colg = (nb << 7) + (c >> 3);
  int k0 = (kb << 6) + (((c & 7) ^ ((c >> 3) & 7)) << 3);
  bf16x8 h8;
#pragma unroll
  for (int j = 0; j < 8; ++j) {
    float w = W[(size_t)(k0 + j) * N + colg];
    h8[j] = (short)f2bf(w);
  }
  *(bf16x8*)(hi + (size_t)g * 8) = h8;
}

// ---------------- MFMA GEMM (LDS-staged): C[Mpad,N] bf16 = A * B ----------
// BM=128, BN in {128,256}, BK=64. Threads = 2*BN (4 or 8 waves), wave tile
// 64x64. grid (N/BN, Mpad/128). AF32: A is fp32, reg-staged with convert.

template <int BN, bool AF32, bool BIAS, bool RELU>
__global__ __launch_bounds__(2 * BN) void mfma_gemm(
    const void* __restrict__ Aptr, const short* __restrict__ Bhi,
    const float* __restrict__ bias, unsigned short* __restrict__ C,
    int M, int N, int K) {
  constexpr int W = BN / 32;       // waves: 4 or 8
  constexpr int RW = 128 / W;      // A rows per wave: 32 or 16
  constexpr int IA = RW / 8;       // A stage issues per thread: 4 or 2
  constexpr int NH = BN / 128;     // 128-col halves
  constexpr int WH = W / NH;       // waves per half: 4
  constexpr int CW = BN / 64;      // wave cols

  __shared__ short As[8192];       // [128 rows][8 kc][8] swizzled image
  __shared__ short Bs[BN * 64];    // [BN cols][8 kc][8]

  const int tid = threadIdx.x;
  const int lane = tid & 63;
  const int wave = tid >> 6;
  const int rowblk = blockIdx.y << 7;
  const int colblk = blockIdx.x * BN;
  const int wr = (wave / CW) << 6;
  const int wc = (wave % CW) << 6;
  const int lr = lane & 15;
  const int lk = lane >> 4;
  const int kbN = K >> 6;
  const int half = wave / WH;
  const int wh = wave % WH;
  const int nb0 = colblk >> 7;

  f32x4 acc[4][4];
#pragma unroll
  for (int i = 0; i < 4; ++i)
#pragma unroll
    for (int j = 0; j < 4; ++j) {
      f32x4 z = {0.f, 0.f, 0.f, 0.f};
      acc[i][j] = z;
    }

  // A staging: wave covers rows [wave*RW, wave*RW+RW); issue i covers 8 rows.
  // LDS dest linear; stored kcs = lane&7 holds global kc = kcs ^ (row&7),
  // row&7 == (lane>>3)&7 (issue offset multiple of 8 rows).
  size_t aoff[IA];
#pragma unroll
  for (int i = 0; i < IA; ++i) {
    int rg = rowblk + wave * RW + i * 8 + (lane >> 3);
    if (AF32) rg = (rg < M) ? rg : (M - 1);  // clamp: pad rows read last row
    aoff[i] = (size_t)rg * K + (size_t)(((lane & 7) ^ ((lane >> 3) & 7)) << 3);
  }
  short* AsW = As + wave * (RW * 64);
  short* BsW = Bs + half * 8192 + wh * 2048;

  for (int kb = 0; kb < kbN; ++kb) {
    const short* bsrc = Bhi + ((size_t)(nb0 + half) * kbN + kb) * 8192 + (size_t)(wh * 256 + lane) * 8;
#pragma unroll
    for (int i = 0; i < 4; ++i)
      gload_lds16(bsrc + i * 512, BsW + i * 512);
#pragma unroll
    for (int i = 0; i < IA; ++i) {
      if (AF32) {
        const float* ap = (const float*)Aptr + aoff[i] + (kb << 6);
        float4 f0 = *(const float4*)ap;
        float4 f1 = *(const float4*)(ap + 4);
        bf16x8 t;
        t[0] = (short)f2bf(f0.x); t[1] = (short)f2bf(f0.y);
        t[2] = (short)f2bf(f0.z); t[3] = (short)f2bf(f0.w);
        t[4] = (short)f2bf(f1.x); t[5] = (short)f2bf(f1.y);
        t[6] = (short)f2bf(f1.z); t[7] = (short)f2bf(f1.w);
        *(bf16x8*)(AsW + i * 512 + lane * 8) = t;
      } else {
        gload_lds16((const unsigned short*)Aptr + aoff[i] + (kb << 6), AsW + i * 512);
      }
    }
    __syncthreads();
#pragma unroll
    for (int kk = 0; kk < 2; ++kk) {
      bf16x8 af[4], bhf[4];
      const int kc = kk * 4 + lk;
#pragma unroll
      for (int rb = 0; rb < 4; ++rb) {
        int rowl = wr + rb * 16 + lr;
        af[rb] = *(const bf16x8*)(As + rowl * 64 + ((kc ^ (rowl & 7)) << 3));
      }
#pragma unroll
      for (int cb = 0; cb < 4; ++cb) {
        int coll = wc + cb * 16 + lr;
        bhf[cb] = *(const bf16x8*)(Bs + coll * 64 + ((kc ^ (coll & 7)) << 3));
      }
#pragma unroll
      for (int rb = 0; rb < 4; ++rb)
#pragma unroll
        for (int cb = 0; cb < 4; ++cb)
          acc[rb][cb] = __builtin_amdgcn_mfma_f32_16x16x32_bf16(af[rb], bhf[cb], acc[rb][cb], 0, 0, 0);
    }
    __syncthreads();
  }

  // epilogue: C/D layout col=lane&15, row=(lane>>4)*4+i
#pragma unroll
  for (int cb = 0; cb < 4; ++cb) {
    int colg = colblk + wc + cb * 16 + lr;
    float badd = BIAS ? bias[colg] : 0.0f;
#pragma unroll
    for (int rb = 0; rb < 4; ++rb) {
#pragma unroll
      for (int i = 0; i < 4; ++i) {
        int row = rowblk + wr + rb * 16 + lk * 4 + i;
        float v = acc[rb][cb][i] + badd;
        if (RELU) v = fmaxf(v, 0.f);
        C[(size_t)row * N + colg] = f2bf(v);
      }
    }
  }
}

// ---------------- aggregation: out[i] = sum_e val[e]*xw[col[e]] + dinv^2*xw[i] ----

template <int PT, bool INF32>
__device__ __forceinline__ void load_row(const void* p, size_t off, float* xv) {
  if (INF32) {
    if (PT == 2) {
      float2 f = *(const float2*)((const float*)p + off);
      xv[0] = f.x; xv[1] = f.y;
    } else {
      float4 f0 = *(const float4*)((const float*)p + off);
      float4 f1 = *(const float4*)((const float*)p + off + 4);
      xv[0] = f0.x; xv[1] = f0.y; xv[2] = f0.z; xv[3] = f0.w;
      xv[4] = f1.x; xv[5] = f1.y; xv[6] = f1.z; xv[7] = f1.w;
    }
  } else {
    if (PT == 2) {
      unsigned int u = *(const unsigned int*)((const unsigned short*)p + off);
      xv[0] = bf2f((unsigned short)(u & 0xffffu));
      xv[1] = bf2f((unsigned short)(u >> 16));
    } else {
      bf16x8 r = *(const bf16x8*)((const short*)p + off);
#pragma unroll
      for (int j = 0; j < 8; ++j) xv[j] = bf2f((unsigned short)r[j]);
    }
  }
}

template <int PT, int UF, bool INF32, bool BIAS, bool RELU, bool W32, bool W16>
__global__ __launch_bounds__(256) void agg_kernel(
    const void* __restrict__ xw, const int2* __restrict__ pk,
    const int* __restrict__ rowPtr, const float* __restrict__ dinv,
    const float* __restrict__ bias, float* __restrict__ out32,
    unsigned short* __restrict__ out16, int n) {
  const int DIM = PT * 64;
  int node = blockIdx.x * 4 + (threadIdx.x >> 6);
  if (node >= n) return;
  int t = threadIdx.x & 63;
  float acc[PT];
#pragma unroll
  for (int q = 0; q < PT; ++q) acc[q] = 0.f;

  int beg = rowPtr[node], end = rowPtr[node + 1];
  int e = beg;
  for (; e + UF <= end; e += UF) {
    int2 p[UF];
    float xv[UF][PT];
#pragma unroll
    for (int u = 0; u < UF; ++u) p[u] = pk[e + u];
#pragma unroll
    for (int u = 0; u < UF; ++u)
      load_row<PT, INF32>(xw, (size_t)p[u].x * DIM + t * PT, xv[u]);
#pragma unroll
    for (int u = 0; u < UF; ++u) {
      float v = __int_as_float(p[u].y);
#pragma unroll
      for (int q = 0; q < PT; ++q) acc[q] += v * xv[u][q];
    }
  }
  for (; e < end; ++e) {
    int2 pe = pk[e];
    float v = __int_as_float(pe.y);
    float xv[PT];
    load_row<PT, INF32>(xw, (size_t)pe.x * DIM + t * PT, xv);
#pragma unroll
    for (int q = 0; q < PT; ++q) acc[q] += v * xv[q];
  }
  float di = dinv[node];
  float sl = di * di;
  {
    float xv[PT];
    load_row<PT, INF32>(xw, (size_t)node * DIM + t * PT, xv);
#pragma unroll
    for (int q = 0; q < PT; ++q) acc[q] += sl * xv[q];
  }
  if (BIAS) {
#pragma unroll
    for (int q = 0; q < PT; ++q) acc[q] += bias[t * PT + q];
  }
  if (RELU) {
#pragma unroll
    for (int q = 0; q < PT; ++q) acc[q] = fmaxf(acc[q], 0.f);
  }
  if (W32) {
    if (PT == 2) {
      float2 o; o.x = acc[0]; o.y = acc[1];
      *(float2*)(out32 + (size_t)node * DIM + t * PT) = o;
    } else {
      float4 o0, o1;
      o0.x = acc[0]; o0.y = acc[1]; o0.z = acc[2]; o0.w = acc[3];
      o1.x = acc[4 % PT]; o1.y = acc[5 % PT]; o1.z = acc[6 % PT]; o1.w = acc[7 % PT];
      *(float4*)(out32 + (size_t)node * DIM + t * PT) = o0;
      *(float4*)(out32 + (size_t)node * DIM + t * PT + 4) = o1;
    }
  }
  if (W16) {
    if (PT == 2) {
      unsigned int u = (unsigned int)f2bf(acc[0]) | ((unsigned int)f2bf(acc[1]) << 16);
      *(unsigned int*)(out16 + (size_t)node * DIM + t * PT) = u;
    } else {
      bf16x8 o;
#pragma unroll
      for (int j = 0; j < PT; ++j) o[j % 8] = (short)f2bf(acc[j]);
      *(bf16x8*)(out16 + (size_t)node * DIM + t * PT) = o;
    }
  }
}

// ---------------------------------------------------------------------------

extern "C" void kernel_launch(void* const* d_in, const int* in_sizes, int n_in,
                              void* d_out, int out_size, void* d_ws, size_t ws_size,
                              hipStream_t stream) {
  const float* x  = (const float*)d_in[0];
  const int*   ei = (const int*)d_in[1];
  const float* ew = (const float*)d_in[2];
  const float* W1 = (const float*)d_in[3];
  const float* b1 = (const float*)d_in[4];
  const float* W2 = (const float*)d_in[5];
  const float* b2 = (const float*)d_in[6];
  const float* W3 = (const float*)d_in[7];
  const float* b3 = (const float*)d_in[8];
  const float* W4 = (const float*)d_in[9];
  const float* b4 = (const float*)d_in[10];

  const int n = in_sizes[0] / 512;         // 50000
  const int E = in_sizes[2];               // 800000
  const int MB128 = (n + 127) / 128;       // 391
  const int Mpad = MB128 * 128;            // 50048

  float* out   = (float*)d_out;
  float* z_out = out + (size_t)n * 512;

  // ---- workspace layout (~127 MB) ----
  char* w = (char*)d_ws;
  auto alloc = [&](size_t bytes) {
    char* p = w;
    w += (bytes + 255) & ~(size_t)255;
    return p;
  };
  float* deg    = (float*)alloc((size_t)n * 4);
  float* dinv   = (float*)alloc((size_t)n * 4);
  int*   cnt    = (int*)alloc((size_t)n * 4);
  int*   rowPtr = (int*)alloc((size_t)(n + 1) * 4);
  int*   fill   = (int*)alloc((size_t)n * 4);
  int*   sums   = (int*)alloc(4096);
  int2*  pk     = (int2*)alloc((size_t)E * 8);
  short* whi1 = (short*)alloc((size_t)512 * 512 * 2);
  short* whi2 = (short*)alloc((size_t)512 * 128 * 2);
  short* whi3 = (short*)alloc((size_t)128 * 512 * 2);
  short* whi4 = (short*)alloc((size_t)512 * 512 * 2);
  unsigned short* T  = (unsigned short*)alloc((size_t)Mpad * 128 * 2);  // xw2 / aggz
  unsigned short* B1 = (unsigned short*)alloc((size_t)Mpad * 512 * 2);  // h / xw4
  unsigned short* B2 = (unsigned short*)alloc((size_t)Mpad * 512 * 2);  // xw1 / zbf / h2

  unsigned short* zbf = B2;  // [n,128] bf16, alive between L2 agg and L3 agg

  const int* srcp = ei;
  const int* dstp = ei + E;

  // ---- graph preprocessing ----
  hipMemsetAsync(deg, 0, (size_t)n * 4, stream);
  hipMemsetAsync(cnt, 0, (size_t)n * 4, stream);
  deg_hist_kernel<<<(E + 255) / 256, 256, 0, stream>>>(dstp, ew, deg, cnt, E);
  dinv_kernel<<<(n + 255) / 256, 256, 0, stream>>>(deg, dinv, n);
  int NB = (n + 511) / 512;
  block_sums_kernel<<<NB, 512, 0, stream>>>(cnt, sums, n);
  scan_sums_kernel<<<1, 512, 0, stream>>>(sums, NB);
  scan_final_kernel<<<NB, 512, 0, stream>>>(cnt, sums, rowPtr, fill, n);
  scatter_edges_kernel<<<(E + 255) / 256, 256, 0, stream>>>(srcp, dstp, ew, dinv, fill, pk, E);

  // ---- weight tiling ----
  tile_w_kernel<<<(4 * 8 * 1024 + 255) / 256, 256, 0, stream>>>(W1, whi1, 512, 512);
  tile_w_kernel<<<(1 * 8 * 1024 + 255) / 256, 256, 0, stream>>>(W2, whi2, 512, 128);
  tile_w_kernel<<<(4 * 2 * 1024 + 255) / 256, 256, 0, stream>>>(W3, whi3, 128, 512);
  tile_w_kernel<<<(4 * 8 * 1024 + 255) / 256, 256, 0, stream>>>(W4, whi4, 512, 512);

  const int AGB = (n + 3) / 4;  // 12500

  // ---- layer 1: xw1 = x@W1 (fp32 A, reg-staged) -> B2 ; h = relu(N.xw1+b1) -> B1 ----
  mfma_gemm<256, true, false, false><<<dim3(2, MB128), 512, 0, stream>>>(
      x, whi1, nullptr, B2, n, 512, 512);
  agg_kernel<8, 4, false, true, true, false, true><<<AGB, 256, 0, stream>>>(
      B2, pk, rowPtr, dinv, b1, nullptr, B1, n);

  // ---- layer 2: xw2 = h@W2 -> T ; z = N.xw2 + b2 -> z_out (fp32) + zbf (bf16) ----
  mfma_gemm<128, false, false, false><<<dim3(1, MB128), 256, 0, stream>>>(
      B1, whi2, nullptr, T, Mpad, 128, 512);
  agg_kernel<2, 8, false, true, false, true, true><<<AGB, 256, 0, stream>>>(
      T, pk, rowPtr, dinv, b2, z_out, zbf, n);

  // ---- layer 3: aggz = N.z (bf16 gather) -> T ; h2 = relu(aggz@W3 + b3) -> B2 ----
  agg_kernel<2, 8, false, false, false, false, true><<<AGB, 256, 0, stream>>>(
      zbf, pk, rowPtr, dinv, nullptr, nullptr, T, n);
  mfma_gemm<256, false, true, true><<<dim3(2, MB128), 512, 0, stream>>>(
      T, whi3, b3, B2, Mpad, 512, 128);

  // ---- layer 4: xw4 = h2@W4 -> B1 ; x_recon = N.xw4 + b4 -> out (fp32) ----
  mfma_gemm<256, false, false, false><<<dim3(2, MB128), 512, 0, stream>>>(
      B2, whi4, nullptr, B1, Mpad, 512, 512);
  agg_kernel<8, 4, false, true, false, true, false><<<AGB, 256, 0, stream>>>(
      B1, pk, rowPtr, dinv, b4, out, nullptr, n);
}